// Round 10
// baseline (558.228 us; speedup 1.0000x reference)
//
#include <hip/hip_runtime.h>
#include <cstdint>

typedef __bf16 bf16_t;
typedef __attribute__((ext_vector_type(8))) __bf16 bf16x8;
typedef __attribute__((ext_vector_type(4))) __bf16 bf16x4;
typedef __attribute__((ext_vector_type(4))) float f32x4;

#define MFMA16(a,b,c) __builtin_amdgcn_mfma_f32_16x16x32_bf16((a),(b),(c),0,0,0)

// ---------------- workspace offsets (float units) ----------------
constexpr size_t PVSTR   = (size_t)2*5*1024*72;  // one N-slice of PV partials
constexpr size_t o_wcatT = 0;                    // bf16 [448][768]
constexpr size_t o_whfT  = o_wcatT + 172032;     // bf16 [128][256]
constexpr size_t o_wvhT  = o_whfT  + 16384;      // bf16 [80][256]  fused Wv@Whv (transposed)
constexpr size_t o_wvh1  = o_wvhT  + 10240;      // f32  [65]  (mask-row of fused weight)
constexpr size_t o_WvT   = o_wvh1  + 80;         // bf16 [512][256]
constexpr size_t o_whh   = o_WvT   + 65536;      // f32  [64][66]
constexpr size_t o_wh2T  = o_whh   + 4224;       // bf16 [64][576]
constexpr size_t o_keyb  = o_wh2T  + 18432;      // bf16 [B*T*1024][64]
constexpr size_t o_ms    = o_keyb  + 1048576;    // f32  [B*T*1024]
constexpr size_t o_qeb   = o_ms    + 32768;      // bf16 [B*T*1024][64]
constexpr size_t o_f16b  = o_qeb   + 1048576;    // bf16 [B*T*1024][256]
constexpr size_t o_qfb   = o_f16b  + 4194304;    // bf16 [B*T*1024][160]
constexpr size_t o_kfb   = o_qfb   + 2621440;    // bf16 [B*3072][160]
constexpr size_t o_vb    = o_kfb   + 491520;     // bf16 [B*3072][512] (slots 0,2 used)
constexpr size_t o_vhT   = o_vb    + 1572864;    // bf16 [B][128][3072] (row65 = ones)
constexpr size_t o_pv    = o_vhT   + 393216;     // f32  [12 slices][B][5][1024][72]
constexpr size_t o_p16   = o_pv    + 12*PVSTR;   // bf16 [B*T*1024][72]
constexpr size_t o_mh    = o_p16   + 1179648;    // f32  [B][15][1024][66]
constexpr size_t o_hid   = o_mh    + 2027520;    // f32  [B][1024][64]
constexpr size_t o_wmk   = o_hid   + 131072;     // f32  [B][1024]
constexpr size_t ws_need = o_wmk   + 2048;

// ---------------- init: transposed bf16 weight panels + zero out[t=0] ----------------
__global__ __launch_bounds__(256)
void k_init(const float* __restrict__ Wk, const float* __restrict__ Wsh,
            const float* __restrict__ Wse, const float* __restrict__ Wf,
            const float* __restrict__ Wv, const float* __restrict__ Wh2,
            const float* __restrict__ Whd, const float* __restrict__ Wdec,
            bf16_t* __restrict__ wcatT, bf16_t* __restrict__ whfT,
            bf16_t* __restrict__ WvT, float* __restrict__ whh,
            bf16_t* __restrict__ wh2T, float* __restrict__ out)
{
    int idx = blockIdx.x*256 + threadIdx.x;
    if (idx < 344064) {                       // wcatT[n][k] n<448 k<768
        int n = idx/768, k = idx%768;
        float v = 0.f;
        if (n < 64)       v = Wk[k*64+n];
        else if (n == 64) v = Wsh[k];
        else if (n < 129) v = Wse[k*64+(n-65)];
        else if (n < 385) v = Wf[k*256+(n-129)];
        wcatT[idx] = (bf16_t)v;
        return;
    }
    idx -= 344064;
    if (idx < 32768) {                        // whfT[c][k] c<128 k<256
        int c = idx/256, k = idx%256;
        float v = 0.f;
        if (c < 64) v = Whd[k*64+c]; else if (c == 64) v = Wdec[k];
        whfT[idx] = (bf16_t)v;
        return;
    }
    idx -= 32768;
    if (idx < 131072) {                       // WvT[n][k] n<512 k<256
        int n = idx/256, k = idx%256;
        WvT[idx] = (bf16_t)Wv[k*512+n];
        return;
    }
    idx -= 131072;
    if (idx < 4224) {                         // whh[k][c] (stride 66), c<65 real
        int k = idx/66, c = idx%66;
        float v = 0.f;
        if (c < 64) v = Whd[(768+k)*64+c]; else if (c == 64) v = Wdec[768+k];
        whh[idx] = v;
        return;
    }
    idx -= 4224;
    if (idx < 36864) {                        // wh2T[c][k] c<64 k<576
        int c = idx/576, k = idx%576;
        wh2T[idx] = (bf16_t)Wh2[k*64+c];
        return;
    }
    idx -= 36864;
    if (idx < 128) {                          // zero out[t=0] (feat0 atomics)
        int b = idx>>6, c = idx&63;
        out[(size_t)b*1024 + c] = 0.f;
    }
}

// ---------------- fused weight: Wvh[k][c] = Wv[k]@whv(:,c); wvh1 = Wv[256]@whv ----------------
__global__ __launch_bounds__(256)
void k_wfuse(const float* __restrict__ Wv, const float* __restrict__ Whd,
             const float* __restrict__ Wdec, bf16_t* __restrict__ wvhT,
             float* __restrict__ wvh1)
{
    int idx = blockIdx.x*256 + threadIdx.x;
    if (idx < 20480) {
        int k = idx / 80, c = idx % 80;
        float s = 0.f;
        if (c < 65) {
            for (int j = 0; j < 512; j++) {
                float hv = (c < 64) ? Whd[(256+j)*64 + c] : Wdec[256 + j];
                s = fmaf(Wv[k*512 + j], hv, s);
            }
        }
        wvhT[(size_t)c*256 + k] = (bf16_t)s;
        return;
    }
    idx -= 20480;
    if (idx < 65) {
        int c = idx;
        float s = 0.f;
        for (int j = 0; j < 512; j++) {
            float hv = (c < 64) ? Whd[(256+j)*64 + c] : Wdec[256 + j];
            s = fmaf(Wv[256*512 + j], hv, s);
        }
        wvh1[c] = s;
    }
}

// ---------------- projection GEMM v3: DIRECT global A-frag loads, no LDS, no barriers ----
// grid (32 ptile, 32 bt), block 256 (4 independent waves).
// A-frag (row p0+fi*16+l15, k=kc*32+l4*8+u): u spans 8 CONSECUTIVE floats of frames
//   addr = fb + (kc>>3)*262144 + (bx*16 + (kc&7)*2 + (l4>>1))*512 + (fi*16+l15)*16 + (l4&1)*8
// -> per-wave contiguous 1KB segments; each frame element read exactly once.
__global__ __launch_bounds__(256)
void k_proj(const float* __restrict__ frames, const bf16_t* __restrict__ wcatT,
            bf16_t* __restrict__ keyb, float* __restrict__ msb,
            bf16_t* __restrict__ qeb, bf16_t* __restrict__ f16b)
{
    const int bx = blockIdx.x, bt = blockIdx.y;
    const int p0 = bx*32;
    const int tid = threadIdx.x, lane = tid & 63, w = tid >> 6;
    const int l15 = lane & 15, l4 = lane >> 4;
    f32x4 acc[2][7] = {};
    const float* fb = frames + (size_t)bt*786432;
    const float* abase = fb + (size_t)(bx*16 + (l4 >> 1))*512 + (l4 & 1)*8;

    #define ALOAD(d0, d1, kc, fi) { \
        const float* s_ = abase + (size_t)((kc) >> 3)*262144 + ((kc) & 7)*1024 \
                        + ((fi)*16 + l15)*16; \
        d0 = *(const float4*)s_; d1 = *(const float4*)(s_ + 4); }
    #define ACVT(dst, v0, v1) { \
        dst[0]=(bf16_t)(v0).x; dst[1]=(bf16_t)(v0).y; dst[2]=(bf16_t)(v0).z; dst[3]=(bf16_t)(v0).w; \
        dst[4]=(bf16_t)(v1).x; dst[5]=(bf16_t)(v1).y; dst[6]=(bf16_t)(v1).z; dst[7]=(bf16_t)(v1).w; }

    float4 c00, c01, c10, c11, n00, n01, n10, n11;
    ALOAD(c00, c01, 0, 0); ALOAD(c10, c11, 0, 1);
    for (int kc = 0; kc < 24; kc++) {
        if (kc + 1 < 24) { ALOAD(n00, n01, kc+1, 0); ALOAD(n10, n11, kc+1, 1); }
        bf16x8 af0, af1;
        ACVT(af0, c00, c01); ACVT(af1, c10, c11);
        #pragma unroll
        for (int fj = 0; fj < 7; fj++) {
            int n = w*112 + fj*16 + l15;
            bf16x8 bv = *(const bf16x8*)(wcatT + (size_t)n*768 + kc*32 + l4*8);
            acc[0][fj] = MFMA16(af0, bv, acc[0][fj]);
            acc[1][fj] = MFMA16(af1, bv, acc[1][fj]);
        }
        c00 = n00; c01 = n01; c10 = n10; c11 = n11;
    }
    #undef ALOAD
    #undef ACVT

    #pragma unroll
    for (int fi = 0; fi < 2; fi++)
    #pragma unroll
    for (int fj = 0; fj < 7; fj++) {
        int nn = w*112 + fj*16 + l15;
        #pragma unroll
        for (int rr = 0; rr < 4; rr++) {
            int pp = p0 + fi*16 + l4*4 + rr;
            float v = acc[fi][fj][rr];
            size_t rowb = (size_t)bt*1024 + pp;
            if (nn < 64)       keyb[rowb*64 + nn] = (bf16_t)v;
            else if (nn == 64) msb[rowb] = v*v + 1.f;
            else if (nn < 129) qeb[rowb*64 + (nn-65)] = (bf16_t)(1.f/(1.f+expf(-v)));
            else if (nn < 385) f16b[rowb*256 + (nn-129)] = (bf16_t)v;
        }
    }
}

// ---------------- Qfeat: [qe*qk | qe | b_sq | zeros] bf16 ----------------
__global__ __launch_bounds__(512)
void k_qf(const bf16_t* __restrict__ keyb, const bf16_t* __restrict__ qeb,
          bf16_t* __restrict__ qfb)
{
    int bt = blockIdx.x;
    int p = blockIdx.y*8 + threadIdx.y;
    int c = threadIdx.x;
    size_t rowb = (size_t)bt*1024 + p;
    float qk = (float)keyb[rowb*64 + c];
    float qv = (float)qeb[rowb*64 + c];
    float bsq = qv*qk*qk;
    #pragma unroll
    for (int off = 32; off; off >>= 1) bsq += __shfl_xor(bsq, off);
    bf16_t* q = qfb + rowb*160;
    q[c]      = (bf16_t)(qv*qk);
    q[64 + c] = (bf16_t)qv;
    if (c == 0) q[128] = (bf16_t)bsq;
    if (c < 31) q[129 + c] = (bf16_t)0.f;
}

// ---------------- t=0 mask: aggregate + 16x16 avg-pool (coalesced) ----------------
__global__ __launch_bounds__(256)
void k_mask0(const float* __restrict__ im, float* __restrict__ wmask)
{
    int blk = blockIdx.x;
    int b = blk >> 5, i = blk & 31;
    int tid = threadIdx.x;
    int xq = tid & 127, yh = tid >> 7;
    const float* base = im + (size_t)b*262144 + (size_t)(i*16)*512;
    float s = 0.f;
    for (int yy = 0; yy < 8; yy++) {
        int y = yy*2 + yh;
        float4 v = *(const float4*)(base + (size_t)y*512 + xq*4);
        float e[4] = {v.x, v.y, v.z, v.w};
        #pragma unroll
        for (int u = 0; u < 4; u++) {
            float pc = fminf(fmaxf(e[u],      1e-7f), 1.f-1e-7f);
            float qc = fminf(fmaxf(1.f-e[u],  1e-7f), 1.f-1e-7f);
            s += pc*pc/(pc*pc + qc*qc);
        }
    }
    __shared__ float red[32];
    if (tid < 32) red[tid] = 0.f;
    __syncthreads();
    atomicAdd(&red[xq >> 2], s);
    __syncthreads();
    if (tid < 32) wmask[b*1024 + i*32 + tid] = red[tid]*(1.f/256.f);
}

// ---------------- per-slot prep: kf rows + vhT GEMM (from f16 + fused weight) ----------------
__global__ __launch_bounds__(256)
void k_prep(const bf16_t* __restrict__ f16b, const bf16_t* __restrict__ keyb,
            const float* __restrict__ msb, const float* __restrict__ wmk,
            const bf16_t* __restrict__ wvhT, const float* __restrict__ wvh1,
            bf16_t* __restrict__ kfb, bf16_t* __restrict__ vhT, int tm, int slot)
{
    int b = blockIdx.y, n0 = blockIdx.x*64;
    int tid = threadIdx.x, lane = tid & 63, w = tid >> 6;
    // ---- kf fill ----
    {
        int row = n0 + (tid >> 2), q = tid & 3;
        size_t rowb = (size_t)(b*16 + tm)*1024 + row;
        float m = msb[rowb];
        bf16_t* kr = kfb + ((size_t)b*3072 + slot*1024 + row)*160;
        bf16x8 k0v = *(const bf16x8*)(keyb + rowb*64 + q*16);
        bf16x8 k1v = *(const bf16x8*)(keyb + rowb*64 + q*16 + 8);
        bf16x8 o0, o1, s0, s1;
        #pragma unroll
        for (int u = 0; u < 8; u++) {
            float mk0 = (float)k0v[u], mk1 = (float)k1v[u];
            o0[u] = (bf16_t)( m*mk0*0.25f);       o1[u] = (bf16_t)( m*mk1*0.25f);
            s0[u] = (bf16_t)(-m*mk0*mk0*0.125f);  s1[u] = (bf16_t)(-m*mk1*mk1*0.125f);
        }
        *(bf16x8*)(kr + q*16)      = o0;  *(bf16x8*)(kr + q*16 + 8)      = o1;
        *(bf16x8*)(kr + 64 + q*16) = s0;  *(bf16x8*)(kr + 64 + q*16 + 8) = s1;
        if (q == 0) kr[128] = (bf16_t)(-m*0.125f);
        else if (q == 1) { for (int u = 0; u < 15; u++) kr[129+u] = (bf16_t)0.f; }
        else if (q == 2) { for (int u = 0; u < 16; u++) kr[144+u] = (bf16_t)0.f; }
    }
    // ---- vh GEMM: 64 n-rows x 80 c, K=256 ----
    int l15 = lane & 15, l4 = lane >> 4;
    const bf16_t* A = f16b + ((size_t)(b*16 + tm)*1024 + n0 + w*16 + l15)*256;
    f32x4 acc[5] = {};
    #pragma unroll
    for (int ks = 0; ks < 8; ks++) {
        bf16x8 a0 = *(const bf16x8*)(A + ks*32 + l4*8);
        #pragma unroll
        for (int cf = 0; cf < 5; cf++) {
            bf16x8 bv = *(const bf16x8*)(wvhT + (size_t)(cf*16 + l15)*256 + ks*32 + l4*8);
            acc[cf] = MFMA16(a0, bv, acc[cf]);
        }
    }
    #pragma unroll
    for (int cf = 0; cf < 5; cf++) {
        int cc = cf*16 + l15;
        float w1 = (cc < 65) ? wvh1[cc] : 0.f;
        #pragma unroll
        for (int rr = 0; rr < 4; rr++) {
            int p = n0 + w*16 + l4*4 + rr;
            float val;
            if (cc < 65)      val = acc[cf][rr] + wmk[b*1024 + p]*w1;
            else              val = (cc == 65) ? 1.f : 0.f;
            vhT[(size_t)b*393216 + (size_t)cc*3072 + slot*1024 + p] = (bf16_t)val;
        }
    }
}

// ---------------- value (MFMA): V = f16 @ Wv[0:256] + wmask*Wv[256] (slots 0,2) ----------------
__global__ __launch_bounds__(256)
void k_value(const bf16_t* __restrict__ f16b, const float* __restrict__ wmk,
             const bf16_t* __restrict__ WvT, const float* __restrict__ Wv,
             bf16_t* __restrict__ vb, int t, int slot)
{
    int b = blockIdx.z;
    int n0 = blockIdx.x*64, p0 = blockIdx.y*64;
    const int tid = threadIdx.x, lane = tid & 63, w = tid >> 6;
    const int wr = w >> 1, wc = w & 1, l15 = lane & 15, l4 = lane >> 4;
    const bf16_t* A = f16b + ((size_t)(b*16 + t)*1024 + p0)*256;
    f32x4 acc[2][2] = {};
    int ar = wr*32 + l15, bc = n0 + wc*32 + l15, koff = l4*8;
    #pragma unroll
    for (int ks = 0; ks < 8; ks++) {
        bf16x8 a0 = *(const bf16x8*)(A + (size_t)ar*256 + ks*32 + koff);
        bf16x8 a1 = *(const bf16x8*)(A + (size_t)(ar+16)*256 + ks*32 + koff);
        bf16x8 b0 = *(const bf16x8*)(WvT + (size_t)bc*256 + ks*32 + koff);
        bf16x8 b1 = *(const bf16x8*)(WvT + (size_t)(bc+16)*256 + ks*32 + koff);
        acc[0][0] = MFMA16(a0, b0, acc[0][0]);
        acc[0][1] = MFMA16(a0, b1, acc[0][1]);
        acc[1][0] = MFMA16(a1, b0, acc[1][0]);
        acc[1][1] = MFMA16(a1, b1, acc[1][1]);
    }
    #pragma unroll
    for (int fi = 0; fi < 2; fi++)
    #pragma unroll
    for (int fj = 0; fj < 2; fj++) {
        int nn = n0 + wc*32 + fj*16 + l15;
        float wvl = Wv[131072 + nn];
        #pragma unroll
        for (int rr = 0; rr < 4; rr++) {
            int pp = p0 + wr*32 + fi*16 + l4*4 + rr;
            float wm = wmk[b*1024 + pp];
            vb[((size_t)b*3072 + slot*1024 + pp)*512 + nn] = (bf16_t)(acc[fi][fj][rr] + wm*wvl);
        }
    }
}

// ---------------- pre16 (MFMA): f16 @ [Whd_lo|Wdec_lo] -> [p][65] ----------------
__global__ __launch_bounds__(256)
void k_pre16(const bf16_t* __restrict__ f16b, const bf16_t* __restrict__ whfT,
             bf16_t* __restrict__ p16b)
{
    int bt = blockIdx.y;
    int p0 = blockIdx.x*64;
    const int tid = threadIdx.x, lane = tid & 63, w = tid >> 6;
    const int wr = w >> 1, wc = w & 1, l15 = lane & 15, l4 = lane >> 4;
    const bf16_t* A = f16b + ((size_t)bt*1024 + p0)*256;
    f32x4 acc[2][4] = {};
    int ar = wr*32 + l15, koff = l4*8;
    #pragma unroll
    for (int ks = 0; ks < 8; ks++) {
        bf16x8 a0 = *(const bf16x8*)(A + (size_t)ar*256 + ks*32 + koff);
        bf16x8 a1 = *(const bf16x8*)(A + (size_t)(ar+16)*256 + ks*32 + koff);
        #pragma unroll
        for (int fj = 0; fj < 4; fj++) {
            int cc = wc*64 + fj*16 + l15;
            bf16x8 bv = *(const bf16x8*)(whfT + (size_t)cc*256 + ks*32 + koff);
            acc[0][fj] = MFMA16(a0, bv, acc[0][fj]);
            acc[1][fj] = MFMA16(a1, bv, acc[1][fj]);
        }
    }
    #pragma unroll
    for (int fi = 0; fi < 2; fi++)
    #pragma unroll
    for (int fj = 0; fj < 4; fj++) {
        int cc = wc*64 + fj*16 + l15;
        if (cc < 65) {
            #pragma unroll
            for (int rr = 0; rr < 4; rr++) {
                int pp = p0 + wr*32 + fi*16 + l4*4 + rr;
                p16b[((size_t)bt*1024 + pp)*72 + cc] = (bf16_t)acc[fi][fj][rr];
            }
        }
    }
}

// ---------------- split-N attention: exp(S)·Vh partials (sim<=0, no max/sum) ----------------
__global__ __launch_bounds__(256)
void k_att(const bf16_t* __restrict__ qfb, const bf16_t* __restrict__ kfb,
           const bf16_t* __restrict__ vhT, float* __restrict__ PVp, int t0)
{
    int b = blockIdx.z & 1, sl = blockIdx.z >> 1;
    int ts = blockIdx.y, t = t0 + ts, p0 = blockIdx.x*64;
    int n_base = sl*256;
    int tid = threadIdx.x, lane = tid & 63, w = tid >> 6;
    int l15 = lane & 15, l4 = lane >> 4;
    __shared__ __align__(16) bf16_t P_lds[4][16][72];

    const bf16_t* Q = qfb + ((size_t)(b*16 + t)*1024 + p0 + w*16 + l15)*160 + l4*8;
    bf16x8 aq[5];
    #pragma unroll
    for (int kc = 0; kc < 5; kc++) aq[kc] = *(const bf16x8*)(Q + kc*32);

    const bf16_t* K  = kfb + ((size_t)b*3072 + n_base)*160;
    const bf16_t* Vh = vhT + (size_t)b*393216 + n_base;
    f32x4 o[5] = {};

    for (int n0 = 0; n0 < 256; n0 += 64) {
        f32x4 s[4] = {};
        #pragma unroll
        for (int kc = 0; kc < 5; kc++) {
            #pragma unroll
            for (int nf = 0; nf < 4; nf++) {
                bf16x8 bk = *(const bf16x8*)(K + (size_t)(n0 + nf*16 + l15)*160 + kc*32 + l4*8);
                s[nf] = MFMA16(aq[kc], bk, s[nf]);
            }
        }
        #pragma unroll
        for (int nf = 0; nf < 4; nf++) {
            #pragma unroll
            for (int rr = 0; rr < 4; rr++) {
                float pe = __expf(s[nf][rr]);
                P_lds[w][l4*4 + rr][nf*16 + l15] = (bf16_t)pe;
            }
        }
        #pragma unroll
        for (int kc2 = 0; kc2 < 2; kc2++) {
            bf16x8 ap = *(const bf16x8*)&P_lds[w][l15][kc2*32 + l4*8];
            #pragma unroll
            for (int cf = 0; cf < 5; cf++) {
                bf16x8 bv = *(const bf16x8*)(Vh + (size_t)(cf*16 + l15)*3072 + n0 + kc2*32 + l4*8);
                o[cf] = MFMA16(ap, bv, o[cf]);
            }
        }
    }
    float* O = PVp + (size_t)sl*PVSTR + ((size_t)((b*5 + ts)*1024) + p0 + w*16)*72;
    #pragma unroll
    for (int cf = 0; cf < 5; cf++) {
        int cc = cf*16 + l15;
        if (cc < 66) {
            #pragma unroll
            for (int rr = 0; rr < 4; rr++)
                O[(size_t)(l4*4 + rr)*72 + cc] = o[cf][rr];
        }
    }
}

// ---------------- sequential 5-step chain; sums PV slices, divides by col65 ----------------
__global__ __launch_bounds__(256)
void k_chain2(const bf16_t* __restrict__ p16b, const float* __restrict__ PVp,
              const float* __restrict__ whhbuf, float* __restrict__ hidden,
              float* __restrict__ wmk, float* __restrict__ mh, int t0, int ph, int ns)
{
    int b = blockIdx.y;
    int tid = threadIdx.x, lane = tid & 63, w = tid >> 6;
    int p = blockIdx.x*4 + w;
    __shared__ float whh_s[64][66];
    __shared__ float hid_s[4][64];
    for (int idx = tid; idx < 64*66; idx += 256) whh_s[idx/66][idx%66] = whhbuf[idx];
    float h = hidden[((size_t)b*1024 + p)*64 + lane];
    hid_s[w][lane] = h;
    __syncthreads();
    float wd = whh_s[lane][64];
    for (int ts = 0; ts < 5; ts++) {
        int t = t0 + ts;
        size_t r16 = ((size_t)(b*16 + t)*1024 + p)*72;
        size_t rpv = ((size_t)((b*5 + ts)*1024) + p)*72;
        float pvc = 0.f, pv64 = 0.f, pv65 = 0.f;
        for (int s2 = 0; s2 < ns; s2++) {
            const float* bp = PVp + (size_t)s2*PVSTR + rpv;
            pvc  += bp[lane];
            pv64 += bp[64];
            pv65 += bp[65];
        }
        float rinv  = 1.f/pv65;
        float pre   = (float)p16b[r16 + lane] + pvc*rinv;
        float fgpre = (float)p16b[r16 + 64]   + pv64*rinv;
        float s = pre;
        #pragma unroll 8
        for (int k = 0; k < 64; k++) s += hid_s[w][k]*whh_s[k][lane];
        float hl = tanhf(s);
        float fgs = hl*wd;
        #pragma unroll
        for (int off = 1; off < 64; off <<= 1) fgs += __shfl_xor(fgs, off);
        float fg = fgpre + fgs;
        float m = 1.f/(1.f+expf(-fg));
        size_t rmh = ((size_t)(b*15 + ph*5 + ts)*1024 + p)*66;
        mh[rmh + lane] = m*hl;
        if (lane == 0) mh[rmh + 64] = m;
        if (ts == 4 && lane == 0) wmk[b*1024 + p] = m;
        h = hl;
        __syncthreads();
        hid_s[w][lane] = h;
        __syncthreads();
    }
    hidden[((size_t)b*1024 + p)*64 + lane] = h;
}

// ---------------- hidden update (MFMA): tanh([V | hid?] @ Wh2) ----------------
__global__ __launch_bounds__(256)
void k_hidm(const bf16_t* __restrict__ vb, const bf16_t* __restrict__ wh2T,
            float* __restrict__ hidden, int vslot, int has_h)
{
    int b = blockIdx.y, p0 = blockIdx.x*64;
    int tid = threadIdx.x, lane = tid & 63, w = tid >> 6;
    int l15 = lane & 15, l4 = lane >> 4;
    int arow = p0 + w*16 + l15;
    const bf16_t* A = vb + ((size_t)b*3072 + vslot*1024 + arow)*512;
    const float* Hp = hidden + ((size_t)b*1024 + arow)*64;
    f32x4 acc[4] = {};
    int kiters = has_h ? 18 : 16;
    for (int ks = 0; ks < kiters; ks++) {
        bf16x8 a0;
        if (ks < 16) a0 = *(const bf16x8*)(A + ks*32 + l4*8);
        else {
            int ko = (ks-16)*32 + l4*8;
            float4 h0 = *(const float4*)(Hp + ko);
            float4 h1 = *(const float4*)(Hp + ko + 4);
            a0[0]=(bf16_t)h0.x; a0[1]=(bf16_t)h0.y; a0[2]=(bf16_t)h0.z; a0[3]=(bf16_t)h0.w;
            a0[4]=(bf16_t)h1.x; a0[5]=(bf16_t)h1.y; a0[6]=(bf16_t)h1.z; a0[7]=(bf16_t)h1.w;
        }
        #pragma unroll
        for (int cf = 0; cf < 4; cf++) {
            bf16x8 bv = *(const bf16x8*)(wh2T + (size_t)(cf*16 + l15)*576 + ks*32 + l4*8);
            acc[cf] = MFMA16(a0, bv, acc[cf]);
        }
    }
    #pragma unroll
    for (int cf = 0; cf < 4; cf++) {
        int cc = cf*16 + l15;
        #pragma unroll
        for (int rr = 0; rr < 4; rr++) {
            int p = p0 + w*16 + l4*4 + rr;
            hidden[((size_t)b*1024 + p)*64 + cc] = tanhf(acc[cf][rr]);
        }
    }
}

// ---------------- feat t=0: mean over spatial of key (parallel + atomic) ----------------
__global__ __launch_bounds__(256)
void k_feat0(const bf16_t* __restrict__ keyb, float* __restrict__ out)
{
    int chunk = blockIdx.x, b = blockIdx.y;
    int tid = threadIdx.x, c = tid & 63, g = tid >> 6;
    const bf16_t* kb = keyb + (size_t)(b*16)*65536;
    float s = 0.f;
    for (int k = 0; k < 16; k++) {
        int p = chunk*64 + g*16 + k;
        s += (float)kb[(size_t)p*64 + c];
    }
    __shared__ float red[4][64];
    red[g][c] = s;
    __syncthreads();
    if (g == 0)
        atomicAdd(&out[(size_t)b*1024 + c],
                  (red[0][c]+red[1][c]+red[2][c]+red[3][c])*(1.f/1024.f));
}

// ---------------- feats t=1..15: weighted mean reduce ----------------
__global__ __launch_bounds__(256)
void k_feats(const float* __restrict__ mh, float* __restrict__ out)
{
    int slot = blockIdx.x, b = blockIdx.y, t = slot + 1;
    int tid = threadIdx.x, c = tid & 63, g = tid >> 6;
    const float* base = mh + (size_t)(b*15 + slot)*1024*66;
    float s = 0.f, sm = 0.f;
    for (int p = g; p < 1024; p += 4) {
        s += base[(size_t)p*66 + c];
        if (c == 0) sm += base[(size_t)p*66 + 64];
    }
    __shared__ float red[4][64];
    __shared__ float redm[4];
    red[g][c] = s;
    if (c == 0) redm[g] = sm;
    __syncthreads();
    if (g == 0) {
        float tot  = red[0][c] + red[1][c] + red[2][c] + red[3][c];
        float totm = redm[0] + redm[1] + redm[2] + redm[3];
        out[(size_t)(b*16 + t)*64 + c] = tot / fmaxf(totm, 1e-6f);
    }
}

// ---------------- host launcher ----------------
extern "C" void kernel_launch(void* const* d_in, const int* in_sizes, int n_in,
                              void* d_out, int out_size, void* d_ws, size_t ws_size,
                              hipStream_t stream)
{
    (void)in_sizes; (void)n_in; (void)out_size;
    if (ws_size < ws_need*sizeof(float)) return;
    const float* frames = (const float*)d_in[0];
    const float* imask  = (const float*)d_in[1];
    const float* Wk   = (const float*)d_in[3];
    const float* Wsh  = (const float*)d_in[4];
    const float* Wse  = (const float*)d_in[5];
    const float* Wf   = (const float*)d_in[6];
    const float* Wv   = (const float*)d_in[7];
    const float* Wh2  = (const float*)d_in[8];
    const float* Whd  = (const float*)d_in[9];
    const float* Wdec = (const float*)d_in[10];
    float* out = (float*)d_out;
    float* ws  = (float*)d_ws;

    bf16_t* wcatT = (bf16_t*)(ws + o_wcatT);
    bf16_t* whfT  = (bf16_t*)(ws + o_whfT);
    bf16_t* wvhT  = (bf16_t*)(ws + o_wvhT);
    float*  wvh1  = ws + o_wvh1;
    bf16_t* WvT   = (bf16_t*)(ws + o_WvT);
    float*  whh   = ws + o_whh;
    bf16_t* wh2T  = (bf16_t*)(ws + o_wh2T);
    bf16_t* keyb  = (bf16_t*)(ws + o_keyb);
    float*  msb   = ws + o_ms;
    bf16_t* qeb   = (bf16_t*)(ws + o_qeb);
    bf16_t* f16b  = (bf16_t*)(ws + o_f16b);
    bf16_t* qfb   = (bf16_t*)(ws + o_qfb);
    bf16_t* kfb   = (bf16_t*)(ws + o_kfb);
    bf16_t* vb    = (bf16_t*)(ws + o_vb);
    bf16_t* vhT   = (bf16_t*)(ws + o_vhT);
    float*  PVp   = ws + o_pv;
    bf16_t* p16b  = (bf16_t*)(ws + o_p16);
    float*  mh    = ws + o_mh;
    float*  hid   = ws + o_hid;
    float*  wmk   = ws + o_wmk;

    k_init<<<2145, 256, 0, stream>>>(Wk, Wsh, Wse, Wf, Wv, Wh2, Whd, Wdec,
                                     wcatT, whfT, WvT, whh, wh2T, out);
    k_wfuse<<<81, 256, 0, stream>>>(Wv, Whd, Wdec, wvhT, wvh1);
    k_proj<<<dim3(32,32), 256, 0, stream>>>(frames, wcatT, keyb, msb, qeb, f16b);
    k_qf<<<dim3(32,128), dim3(64,8), 0, stream>>>(keyb, qeb, qfb);
    k_mask0<<<64, 256, 0, stream>>>(imask, wmk);
    k_prep<<<dim3(16,2), 256, 0, stream>>>(f16b, keyb, msb, wmk, wvhT, wvh1, kfb, vhT, 0, 0);
    k_value<<<dim3(8,16,2), 256, 0, stream>>>(f16b, wmk, WvT, Wv, vb, 0, 0);
    k_hidm<<<dim3(16,2), 256, 0, stream>>>(vb, wh2T, hid, 0, 0);
    k_feat0<<<dim3(16,2), 256, 0, stream>>>(keyb, out);
    k_pre16<<<dim3(16,32), 256, 0, stream>>>(f16b, whfT, p16b);

    for (int ph = 0; ph < 3; ph++) {
        int t0 = 1 + ph*5;
        int ns = (ph + 1)*4;            // N/256 slices: 4, 8, 12
        k_att<<<dim3(16,5,2*ns), 256, 0, stream>>>(qfb, kfb, vhT, PVp, t0);
        k_chain2<<<dim3(256,2), 256, 0, stream>>>(p16b, PVp, whh, hid, wmk, mh, t0, ph, ns);
        if (ph < 2) {
            int tm = t0 + 4, slot = ph + 1;
            k_prep<<<dim3(16,2), 256, 0, stream>>>(f16b, keyb, msb, wmk, wvhT, wvh1, kfb, vhT, tm, slot);
            if (ph == 1) {
                k_value<<<dim3(8,16,2), 256, 0, stream>>>(f16b, wmk, WvT, Wv, vb, tm, slot);
                k_hidm<<<dim3(16,2), 256, 0, stream>>>(vb, wh2T, hid, 2, 1);
            }
        }
    }
    k_feats<<<dim3(15,2), 256, 0, stream>>>(mh, out);
}

// Round 11
// 536.187 us; speedup vs baseline: 1.0411x; 1.0411x over previous
//
#include <hip/hip_runtime.h>
#include <cstdint>

typedef __bf16 bf16_t;
typedef __attribute__((ext_vector_type(8))) __bf16 bf16x8;
typedef __attribute__((ext_vector_type(4))) __bf16 bf16x4;
typedef __attribute__((ext_vector_type(4))) float f32x4;

#define MFMA16(a,b,c) __builtin_amdgcn_mfma_f32_16x16x32_bf16((a),(b),(c),0,0,0)

// ---------------- workspace offsets (float units) ----------------
constexpr size_t PVSTR   = (size_t)2*5*1024*72;  // one N-slice of PV partials
constexpr size_t o_wcatT = 0;                    // bf16 [448][768]
constexpr size_t o_whfT  = o_wcatT + 172032;     // bf16 [128][256]
constexpr size_t o_wvhT  = o_whfT  + 16384;      // bf16 [80][256]  fused Wv@Whv (transposed)
constexpr size_t o_wvh1  = o_wvhT  + 10240;      // f32  [65]  (mask-row of fused weight)
constexpr size_t o_WvT   = o_wvh1  + 80;         // bf16 [512][256]
constexpr size_t o_whh   = o_WvT   + 65536;      // f32  [64][66]
constexpr size_t o_wh2T  = o_whh   + 4224;       // bf16 [64][576]
constexpr size_t o_keyb  = o_wh2T  + 18432;      // bf16 [B*T*1024][64]
constexpr size_t o_ms    = o_keyb  + 1048576;    // f32  [B*T*1024]
constexpr size_t o_qeb   = o_ms    + 32768;      // bf16 [B*T*1024][64]
constexpr size_t o_f16b  = o_qeb   + 1048576;    // bf16 [B*T*1024][256]
constexpr size_t o_qfb   = o_f16b  + 4194304;    // bf16 [B*T*1024][160]
constexpr size_t o_kfb   = o_qfb   + 2621440;    // bf16 [B*3072][160]
constexpr size_t o_vb    = o_kfb   + 491520;     // bf16 [B*3072][512] (slots 0,2 used)
constexpr size_t o_vhT   = o_vb    + 1572864;    // bf16 [B][128][3072] (row65 = ones)
constexpr size_t o_pv    = o_vhT   + 393216;     // f32  [12 slices][B][5][1024][72]
constexpr size_t o_p16   = o_pv    + 12*PVSTR;   // bf16 [B*T*1024][72]
constexpr size_t o_mh    = o_p16   + 1179648;    // f32  [B][15][1024][66]
constexpr size_t o_hid   = o_mh    + 2027520;    // f32  [B][1024][64]
constexpr size_t o_wmk   = o_hid   + 131072;     // f32  [B][1024]
constexpr size_t ws_need = o_wmk   + 2048;

// ---------------- init: weight panels + fused Wv@Whv + zero out[t=0] ----------------
__global__ __launch_bounds__(256)
void k_init(const float* __restrict__ Wk, const float* __restrict__ Wsh,
            const float* __restrict__ Wse, const float* __restrict__ Wf,
            const float* __restrict__ Wv, const float* __restrict__ Wh2,
            const float* __restrict__ Whd, const float* __restrict__ Wdec,
            bf16_t* __restrict__ wcatT, bf16_t* __restrict__ whfT,
            bf16_t* __restrict__ WvT, float* __restrict__ whh,
            bf16_t* __restrict__ wh2T, float* __restrict__ out,
            bf16_t* __restrict__ wvhT, float* __restrict__ wvh1)
{
    int idx = blockIdx.x*256 + threadIdx.x;
    if (idx < 344064) {                       // wcatT[n][k] n<448 k<768
        int n = idx/768, k = idx%768;
        float v = 0.f;
        if (n < 64)       v = Wk[k*64+n];
        else if (n == 64) v = Wsh[k];
        else if (n < 129) v = Wse[k*64+(n-65)];
        else if (n < 385) v = Wf[k*256+(n-129)];
        wcatT[idx] = (bf16_t)v;
        return;
    }
    idx -= 344064;
    if (idx < 32768) {                        // whfT[c][k] c<128 k<256
        int c = idx/256, k = idx%256;
        float v = 0.f;
        if (c < 64) v = Whd[k*64+c]; else if (c == 64) v = Wdec[k];
        whfT[idx] = (bf16_t)v;
        return;
    }
    idx -= 32768;
    if (idx < 131072) {                       // WvT[n][k] n<512 k<256
        int n = idx/256, k = idx%256;
        WvT[idx] = (bf16_t)Wv[k*512+n];
        return;
    }
    idx -= 131072;
    if (idx < 4224) {                         // whh[k][c] (stride 66), c<65 real
        int k = idx/66, c = idx%66;
        float v = 0.f;
        if (c < 64) v = Whd[(768+k)*64+c]; else if (c == 64) v = Wdec[768+k];
        whh[idx] = v;
        return;
    }
    idx -= 4224;
    if (idx < 36864) {                        // wh2T[c][k] c<64 k<576
        int c = idx/576, k = idx%576;
        wh2T[idx] = (bf16_t)Wh2[k*64+c];
        return;
    }
    idx -= 36864;
    if (idx < 128) {                          // zero out[t=0] (feat0 atomics)
        int b = idx>>6, c = idx&63;
        out[(size_t)b*1024 + c] = 0.f;
        return;
    }
    idx -= 128;
    if (idx < 20480) {                        // wvhT[c][k] = (Wv@whv)[k][c]
        int k = idx / 80, c = idx % 80;
        float s = 0.f;
        if (c < 65) {
            for (int j = 0; j < 512; j++) {
                float hv = (c < 64) ? Whd[(256+j)*64 + c] : Wdec[256 + j];
                s = fmaf(Wv[k*512 + j], hv, s);
            }
        }
        wvhT[(size_t)c*256 + k] = (bf16_t)s;
        return;
    }
    idx -= 20480;
    if (idx < 65) {                           // mask-row of fused weight
        int c = idx;
        float s = 0.f;
        for (int j = 0; j < 512; j++) {
            float hv = (c < 64) ? Whd[(256+j)*64 + c] : Wdec[256 + j];
            s = fmaf(Wv[256*512 + j], hv, s);
        }
        wvh1[c] = s;
    }
}

// ---------------- projection GEMM v4: 64x448 tile, 8 waves, LDS-staged A (once), ----
// contiguous global loads, 2-deep reg prefetch, 1 barrier/chunk, XOR-swizzled LDS.
// grid (16, 32), block 512. waves: wp = w>>2 (p half), wn = w&3 (n quarter).
__global__ __launch_bounds__(512)
void k_proj(const float* __restrict__ frames, const bf16_t* __restrict__ wcatT,
            bf16_t* __restrict__ keyb, float* __restrict__ msb,
            bf16_t* __restrict__ qeb, bf16_t* __restrict__ f16b)
{
    const int bx = blockIdx.x, bt = blockIdx.y;
    const int p0 = bx*64;
    const int tid = threadIdx.x, lane = tid & 63, w = tid >> 6;
    const int wp = w >> 2, wn = w & 3;
    const int l15 = lane & 15, l4 = lane >> 4;
    __shared__ __align__(16) bf16_t Al[2][4][512];     // [buf][imgrow r][512 bf16] = 8KB
    f32x4 acc[2][7] = {};
    const float* fb = frames + (size_t)bt*786432;

    // loader: thread -> r = tid>>7 in [0,4), 4 consecutive floats at (tid&127)*4
    const int lr = tid >> 7, lxb = (tid & 127)*8;       // lxb = byte offset (bf16) in row
    const float* gbase = fb + (size_t)((bx*2 + (lr>>1))*16 + (lr&1))*512 + (tid & 127)*4;
    const int wbyte = lr*1024 + (lxb ^ (((lxb>>7)&3)<<4));
    // frag read: r = wp*2 + (l4>>1); inner byte = l15*32 + (l4&1)*16 (+ fi*512)
    const int rb_in = l15*32 + (l4&1)*16;
    const int rbyte = (wp*2 + (l4>>1))*1024 + (rb_in ^ (((rb_in>>7)&3)<<4));
    char* lds = (char*)&Al[0][0][0];

    #define PLOAD(dst, kc) dst = *(const float4*)(gbase + (size_t)((kc)>>3)*262144 + (size_t)(((kc)&7)*2)*512)
    #define PSTORE(buf, v) { bf16x4 pk; pk[0]=(bf16_t)(v).x; pk[1]=(bf16_t)(v).y; \
        pk[2]=(bf16_t)(v).z; pk[3]=(bf16_t)(v).w; \
        *(bf16x4*)(lds + (buf)*4096 + wbyte) = pk; }

    float4 va, vb;
    PLOAD(va, 0); PLOAD(vb, 1);
    PSTORE(0, va); PLOAD(va, 2);
    PSTORE(1, vb); PLOAD(vb, 3);
    __syncthreads();

    for (int kc = 0; kc < 24; kc++) {
        const int buf = kc & 1;
        bf16x8 af0 = *(const bf16x8*)(lds + buf*4096 + rbyte);
        bf16x8 af1 = *(const bf16x8*)(lds + buf*4096 + rbyte + 512);
        __syncthreads();                       // reads of buf done; prev stores visible
        if (kc < 22) {
            if (buf == 0) { PSTORE(0, va); if (kc < 20) PLOAD(va, kc+4); }
            else          { PSTORE(1, vb); if (kc < 20) PLOAD(vb, kc+4); }
        }
        #pragma unroll
        for (int fj = 0; fj < 7; fj++) {
            int n = wn*112 + fj*16 + l15;
            bf16x8 bv = *(const bf16x8*)(wcatT + (size_t)n*768 + kc*32 + l4*8);
            acc[0][fj] = MFMA16(af0, bv, acc[0][fj]);
            acc[1][fj] = MFMA16(af1, bv, acc[1][fj]);
        }
    }
    #undef PLOAD
    #undef PSTORE

    #pragma unroll
    for (int fi = 0; fi < 2; fi++)
    #pragma unroll
    for (int fj = 0; fj < 7; fj++) {
        int nn = wn*112 + fj*16 + l15;
        #pragma unroll
        for (int rr = 0; rr < 4; rr++) {
            int pp = p0 + wp*32 + fi*16 + l4*4 + rr;
            float v = acc[fi][fj][rr];
            size_t rowb = (size_t)bt*1024 + pp;
            if (nn < 64)       keyb[rowb*64 + nn] = (bf16_t)v;
            else if (nn == 64) msb[rowb] = v*v + 1.f;
            else if (nn < 129) qeb[rowb*64 + (nn-65)] = (bf16_t)(1.f/(1.f+expf(-v)));
            else if (nn < 385) f16b[rowb*256 + (nn-129)] = (bf16_t)v;
        }
    }
}

// ---------------- Qfeat + fused feat0 partial reduce ----------------
// grid (32 bt, 128), block (64,8)
__global__ __launch_bounds__(512)
void k_qf(const bf16_t* __restrict__ keyb, const bf16_t* __restrict__ qeb,
          bf16_t* __restrict__ qfb, float* __restrict__ out)
{
    int bt = blockIdx.x;
    int p = blockIdx.y*8 + threadIdx.y;
    int c = threadIdx.x;
    size_t rowb = (size_t)bt*1024 + p;
    float qk = (float)keyb[rowb*64 + c];
    float qv = (float)qeb[rowb*64 + c];
    float bsq = qv*qk*qk;
    #pragma unroll
    for (int off = 32; off; off >>= 1) bsq += __shfl_xor(bsq, off);
    bf16_t* q = qfb + rowb*160;
    q[c]      = (bf16_t)(qv*qk);
    q[64 + c] = (bf16_t)qv;
    if (c == 0) q[128] = (bf16_t)bsq;
    if (c < 31) q[129 + c] = (bf16_t)0.f;
    if ((bt & 15) == 0) {                      // t==0: feat0 = mean over p of key
        __shared__ float fred[64];
        if (threadIdx.y == 0) fred[c] = 0.f;
        __syncthreads();
        atomicAdd(&fred[c], qk);
        __syncthreads();
        if (threadIdx.y == 0)
            atomicAdd(&out[(size_t)(bt >> 4)*1024 + c], fred[c]*(1.f/1024.f));
    }
}

// ---------------- t=0 mask: aggregate + 16x16 avg-pool (coalesced) ----------------
__global__ __launch_bounds__(256)
void k_mask0(const float* __restrict__ im, float* __restrict__ wmask)
{
    int blk = blockIdx.x;
    int b = blk >> 5, i = blk & 31;
    int tid = threadIdx.x;
    int xq = tid & 127, yh = tid >> 7;
    const float* base = im + (size_t)b*262144 + (size_t)(i*16)*512;
    float s = 0.f;
    for (int yy = 0; yy < 8; yy++) {
        int y = yy*2 + yh;
        float4 v = *(const float4*)(base + (size_t)y*512 + xq*4);
        float e[4] = {v.x, v.y, v.z, v.w};
        #pragma unroll
        for (int u = 0; u < 4; u++) {
            float pc = fminf(fmaxf(e[u],      1e-7f), 1.f-1e-7f);
            float qc = fminf(fmaxf(1.f-e[u],  1e-7f), 1.f-1e-7f);
            s += pc*pc/(pc*pc + qc*qc);
        }
    }
    __shared__ float red[32];
    if (tid < 32) red[tid] = 0.f;
    __syncthreads();
    atomicAdd(&red[xq >> 2], s);
    __syncthreads();
    if (tid < 32) wmask[b*1024 + i*32 + tid] = red[tid]*(1.f/256.f);
}

// ---------------- per-slot prep: kf rows + vhT GEMM ----------------
// grid (32, 2), block 128 (2 waves, 32 rows per block)
__global__ __launch_bounds__(128)
void k_prep(const bf16_t* __restrict__ f16b, const bf16_t* __restrict__ keyb,
            const float* __restrict__ msb, const float* __restrict__ wmk,
            const bf16_t* __restrict__ wvhT, const float* __restrict__ wvh1,
            bf16_t* __restrict__ kfb, bf16_t* __restrict__ vhT, int tm, int slot)
{
    int b = blockIdx.y, n0 = blockIdx.x*32;
    int tid = threadIdx.x, lane = tid & 63, w = tid >> 6;
    // ---- kf fill ----
    {
        int row = n0 + (tid >> 2), q = tid & 3;
        size_t rowb = (size_t)(b*16 + tm)*1024 + row;
        float m = msb[rowb];
        bf16_t* kr = kfb + ((size_t)b*3072 + slot*1024 + row)*160;
        bf16x8 k0v = *(const bf16x8*)(keyb + rowb*64 + q*16);
        bf16x8 k1v = *(const bf16x8*)(keyb + rowb*64 + q*16 + 8);
        bf16x8 o0, o1, s0, s1;
        #pragma unroll
        for (int u = 0; u < 8; u++) {
            float mk0 = (float)k0v[u], mk1 = (float)k1v[u];
            o0[u] = (bf16_t)( m*mk0*0.25f);       o1[u] = (bf16_t)( m*mk1*0.25f);
            s0[u] = (bf16_t)(-m*mk0*mk0*0.125f);  s1[u] = (bf16_t)(-m*mk1*mk1*0.125f);
        }
        *(bf16x8*)(kr + q*16)      = o0;  *(bf16x8*)(kr + q*16 + 8)      = o1;
        *(bf16x8*)(kr + 64 + q*16) = s0;  *(bf16x8*)(kr + 64 + q*16 + 8) = s1;
        if (q == 0) kr[128] = (bf16_t)(-m*0.125f);
        else if (q == 1) { for (int u = 0; u < 15; u++) kr[129+u] = (bf16_t)0.f; }
        else if (q == 2) { for (int u = 0; u < 16; u++) kr[144+u] = (bf16_t)0.f; }
    }
    // ---- vh GEMM: 32 n-rows x 80 c, K=256 ----
    int l15 = lane & 15, l4 = lane >> 4;
    const bf16_t* A = f16b + ((size_t)(b*16 + tm)*1024 + n0 + w*16 + l15)*256;
    f32x4 acc[5] = {};
    #pragma unroll
    for (int ks = 0; ks < 8; ks++) {
        bf16x8 a0 = *(const bf16x8*)(A + ks*32 + l4*8);
        #pragma unroll
        for (int cf = 0; cf < 5; cf++) {
            bf16x8 bv = *(const bf16x8*)(wvhT + (size_t)(cf*16 + l15)*256 + ks*32 + l4*8);
            acc[cf] = MFMA16(a0, bv, acc[cf]);
        }
    }
    #pragma unroll
    for (int cf = 0; cf < 5; cf++) {
        int cc = cf*16 + l15;
        float w1 = (cc < 65) ? wvh1[cc] : 0.f;
        #pragma unroll
        for (int rr = 0; rr < 4; rr++) {
            int p = n0 + w*16 + l4*4 + rr;
            float val;
            if (cc < 65)      val = acc[cf][rr] + wmk[b*1024 + p]*w1;
            else              val = (cc == 65) ? 1.f : 0.f;
            vhT[(size_t)b*393216 + (size_t)cc*3072 + slot*1024 + p] = (bf16_t)val;
        }
    }
}

// ---------------- value (MFMA): V = f16 @ Wv[0:256] + wmask*Wv[256] (slots 0,2) ----------------
__global__ __launch_bounds__(256)
void k_value(const bf16_t* __restrict__ f16b, const float* __restrict__ wmk,
             const bf16_t* __restrict__ WvT, const float* __restrict__ Wv,
             bf16_t* __restrict__ vb, int t, int slot)
{
    int b = blockIdx.z;
    int n0 = blockIdx.x*64, p0 = blockIdx.y*64;
    const int tid = threadIdx.x, lane = tid & 63, w = tid >> 6;
    const int wr = w >> 1, wc = w & 1, l15 = lane & 15, l4 = lane >> 4;
    const bf16_t* A = f16b + ((size_t)(b*16 + t)*1024 + p0)*256;
    f32x4 acc[2][2] = {};
    int ar = wr*32 + l15, bc = n0 + wc*32 + l15, koff = l4*8;
    #pragma unroll
    for (int ks = 0; ks < 8; ks++) {
        bf16x8 a0 = *(const bf16x8*)(A + (size_t)ar*256 + ks*32 + koff);
        bf16x8 a1 = *(const bf16x8*)(A + (size_t)(ar+16)*256 + ks*32 + koff);
        bf16x8 b0 = *(const bf16x8*)(WvT + (size_t)bc*256 + ks*32 + koff);
        bf16x8 b1 = *(const bf16x8*)(WvT + (size_t)(bc+16)*256 + ks*32 + koff);
        acc[0][0] = MFMA16(a0, b0, acc[0][0]);
        acc[0][1] = MFMA16(a0, b1, acc[0][1]);
        acc[1][0] = MFMA16(a1, b0, acc[1][0]);
        acc[1][1] = MFMA16(a1, b1, acc[1][1]);
    }
    #pragma unroll
    for (int fi = 0; fi < 2; fi++)
    #pragma unroll
    for (int fj = 0; fj < 2; fj++) {
        int nn = n0 + wc*32 + fj*16 + l15;
        float wvl = Wv[131072 + nn];
        #pragma unroll
        for (int rr = 0; rr < 4; rr++) {
            int pp = p0 + wr*32 + fi*16 + l4*4 + rr;
            float wm = wmk[b*1024 + pp];
            vb[((size_t)b*3072 + slot*1024 + pp)*512 + nn] = (bf16_t)(acc[fi][fj][rr] + wm*wvl);
        }
    }
}

// ---------------- pre16 (MFMA): f16 @ [Whd_lo|Wdec_lo] -> [p][65] ----------------
__global__ __launch_bounds__(256)
void k_pre16(const bf16_t* __restrict__ f16b, const bf16_t* __restrict__ whfT,
             bf16_t* __restrict__ p16b)
{
    int bt = blockIdx.y;
    int p0 = blockIdx.x*64;
    const int tid = threadIdx.x, lane = tid & 63, w = tid >> 6;
    const int wr = w >> 1, wc = w & 1, l15 = lane & 15, l4 = lane >> 4;
    const bf16_t* A = f16b + ((size_t)bt*1024 + p0)*256;
    f32x4 acc[2][4] = {};
    int ar = wr*32 + l15, koff = l4*8;
    #pragma unroll
    for (int ks = 0; ks < 8; ks++) {
        bf16x8 a0 = *(const bf16x8*)(A + (size_t)ar*256 + ks*32 + koff);
        bf16x8 a1 = *(const bf16x8*)(A + (size_t)(ar+16)*256 + ks*32 + koff);
        #pragma unroll
        for (int fj = 0; fj < 4; fj++) {
            int cc = wc*64 + fj*16 + l15;
            bf16x8 bv = *(const bf16x8*)(whfT + (size_t)cc*256 + ks*32 + koff);
            acc[0][fj] = MFMA16(a0, bv, acc[0][fj]);
            acc[1][fj] = MFMA16(a1, bv, acc[1][fj]);
        }
    }
    #pragma unroll
    for (int fi = 0; fi < 2; fi++)
    #pragma unroll
    for (int fj = 0; fj < 4; fj++) {
        int cc = wc*64 + fj*16 + l15;
        if (cc < 65) {
            #pragma unroll
            for (int rr = 0; rr < 4; rr++) {
                int pp = p0 + wr*32 + fi*16 + l4*4 + rr;
                p16b[((size_t)bt*1024 + pp)*72 + cc] = (bf16_t)acc[fi][fj][rr];
            }
        }
    }
}

// ---------------- split-N attention: exp(S)·Vh partials (sim<=0, no max/sum) ----------------
__global__ __launch_bounds__(256)
void k_att(const bf16_t* __restrict__ qfb, const bf16_t* __restrict__ kfb,
           const bf16_t* __restrict__ vhT, float* __restrict__ PVp, int t0)
{
    int b = blockIdx.z & 1, sl = blockIdx.z >> 1;
    int ts = blockIdx.y, t = t0 + ts, p0 = blockIdx.x*64;
    int n_base = sl*256;
    int tid = threadIdx.x, lane = tid & 63, w = tid >> 6;
    int l15 = lane & 15, l4 = lane >> 4;
    __shared__ __align__(16) bf16_t P_lds[4][16][72];

    const bf16_t* Q = qfb + ((size_t)(b*16 + t)*1024 + p0 + w*16 + l15)*160 + l4*8;
    bf16x8 aq[5];
    #pragma unroll
    for (int kc = 0; kc < 5; kc++) aq[kc] = *(const bf16x8*)(Q + kc*32);

    const bf16_t* K  = kfb + ((size_t)b*3072 + n_base)*160;
    const bf16_t* Vh = vhT + (size_t)b*393216 + n_base;
    f32x4 o[5] = {};

    for (int n0 = 0; n0 < 256; n0 += 64) {
        f32x4 s[4] = {};
        #pragma unroll
        for (int kc = 0; kc < 5; kc++) {
            #pragma unroll
            for (int nf = 0; nf < 4; nf++) {
                bf16x8 bk = *(const bf16x8*)(K + (size_t)(n0 + nf*16 + l15)*160 + kc*32 + l4*8);
                s[nf] = MFMA16(aq[kc], bk, s[nf]);
            }
        }
        #pragma unroll
        for (int nf = 0; nf < 4; nf++) {
            #pragma unroll
            for (int rr = 0; rr < 4; rr++) {
                float pe = __expf(s[nf][rr]);
                P_lds[w][l4*4 + rr][nf*16 + l15] = (bf16_t)pe;
            }
        }
        #pragma unroll
        for (int kc2 = 0; kc2 < 2; kc2++) {
            bf16x8 ap = *(const bf16x8*)&P_lds[w][l15][kc2*32 + l4*8];
            #pragma unroll
            for (int cf = 0; cf < 5; cf++) {
                bf16x8 bv = *(const bf16x8*)(Vh + (size_t)(cf*16 + l15)*3072 + n0 + kc2*32 + l4*8);
                o[cf] = MFMA16(ap, bv, o[cf]);
            }
        }
    }
    float* O = PVp + (size_t)sl*PVSTR + ((size_t)((b*5 + ts)*1024) + p0 + w*16)*72;
    #pragma unroll
    for (int cf = 0; cf < 5; cf++) {
        int cc = cf*16 + l15;
        if (cc < 66) {
            #pragma unroll
            for (int rr = 0; rr < 4; rr++)
                O[(size_t)(l4*4 + rr)*72 + cc] = o[cf][rr];
        }
    }
}

// ---------------- sequential 5-step chain; sums PV slices, divides by col65 ----------------
__global__ __launch_bounds__(256)
void k_chain2(const bf16_t* __restrict__ p16b, const float* __restrict__ PVp,
              const float* __restrict__ whhbuf, float* __restrict__ hidden,
              float* __restrict__ wmk, float* __restrict__ mh, int t0, int ph, int ns)
{
    int b = blockIdx.y;
    int tid = threadIdx.x, lane = tid & 63, w = tid >> 6;
    int p = blockIdx.x*4 + w;
    __shared__ float whh_s[64][66];
    __shared__ float hid_s[4][64];
    for (int idx = tid; idx < 64*66; idx += 256) whh_s[idx/66][idx%66] = whhbuf[idx];
    float h = hidden[((size_t)b*1024 + p)*64 + lane];
    hid_s[w][lane] = h;
    __syncthreads();
    float wd = whh_s[lane][64];
    for (int ts = 0; ts < 5; ts++) {
        int t = t0 + ts;
        size_t r16 = ((size_t)(b*16 + t)*1024 + p)*72;
        size_t rpv = ((size_t)((b*5 + ts)*1024) + p)*72;
        float pvc = 0.f, pv64 = 0.f, pv65 = 0.f;
        for (int s2 = 0; s2 < ns; s2++) {
            const float* bp = PVp + (size_t)s2*PVSTR + rpv;
            pvc  += bp[lane];
            pv64 += bp[64];
            pv65 += bp[65];
        }
        float rinv  = 1.f/pv65;
        float pre   = (float)p16b[r16 + lane] + pvc*rinv;
        float fgpre = (float)p16b[r16 + 64]   + pv64*rinv;
        float s = pre;
        #pragma unroll 8
        for (int k = 0; k < 64; k++) s += hid_s[w][k]*whh_s[k][lane];
        float hl = tanhf(s);
        float fgs = hl*wd;
        #pragma unroll
        for (int off = 1; off < 64; off <<= 1) fgs += __shfl_xor(fgs, off);
        float fg = fgpre + fgs;
        float m = 1.f/(1.f+expf(-fg));
        size_t rmh = ((size_t)(b*15 + ph*5 + ts)*1024 + p)*66;
        mh[rmh + lane] = m*hl;
        if (lane == 0) mh[rmh + 64] = m;
        if (ts == 4 && lane == 0) wmk[b*1024 + p] = m;
        h = hl;
        __syncthreads();
        hid_s[w][lane] = h;
        __syncthreads();
    }
    hidden[((size_t)b*1024 + p)*64 + lane] = h;
}

// ---------------- hidden update (MFMA): tanh([V | hid?] @ Wh2) ----------------
__global__ __launch_bounds__(256)
void k_hidm(const bf16_t* __restrict__ vb, const bf16_t* __restrict__ wh2T,
            float* __restrict__ hidden, int vslot, int has_h)
{
    int b = blockIdx.y, p0 = blockIdx.x*64;
    int tid = threadIdx.x, lane = tid & 63, w = tid >> 6;
    int l15 = lane & 15, l4 = lane >> 4;
    int arow = p0 + w*16 + l15;
    const bf16_t* A = vb + ((size_t)b*3072 + vslot*1024 + arow)*512;
    const float* Hp = hidden + ((size_t)b*1024 + arow)*64;
    f32x4 acc[4] = {};
    int kiters = has_h ? 18 : 16;
    for (int ks = 0; ks < kiters; ks++) {
        bf16x8 a0;
        if (ks < 16) a0 = *(const bf16x8*)(A + ks*32 + l4*8);
        else {
            int ko = (ks-16)*32 + l4*8;
            float4 h0 = *(const float4*)(Hp + ko);
            float4 h1 = *(const float4*)(Hp + ko + 4);
            a0[0]=(bf16_t)h0.x; a0[1]=(bf16_t)h0.y; a0[2]=(bf16_t)h0.z; a0[3]=(bf16_t)h0.w;
            a0[4]=(bf16_t)h1.x; a0[5]=(bf16_t)h1.y; a0[6]=(bf16_t)h1.z; a0[7]=(bf16_t)h1.w;
        }
        #pragma unroll
        for (int cf = 0; cf < 4; cf++) {
            bf16x8 bv = *(const bf16x8*)(wh2T + (size_t)(cf*16 + l15)*576 + ks*32 + l4*8);
            acc[cf] = MFMA16(a0, bv, acc[cf]);
        }
    }
    #pragma unroll
    for (int cf = 0; cf < 4; cf++) {
        int cc = cf*16 + l15;
        #pragma unroll
        for (int rr = 0; rr < 4; rr++) {
            int p = p0 + w*16 + l4*4 + rr;
            hidden[((size_t)b*1024 + p)*64 + cc] = tanhf(acc[cf][rr]);
        }
    }
}

// ---------------- feats t=1..15: weighted mean reduce ----------------
__global__ __launch_bounds__(256)
void k_feats(const float* __restrict__ mh, float* __restrict__ out)
{
    int slot = blockIdx.x, b = blockIdx.y, t = slot + 1;
    int tid = threadIdx.x, c = tid & 63, g = tid >> 6;
    const float* base = mh + (size_t)(b*15 + slot)*1024*66;
    float s = 0.f, sm = 0.f;
    for (int p = g; p < 1024; p += 4) {
        s += base[(size_t)p*66 + c];
        if (c == 0) sm += base[(size_t)p*66 + 64];
    }
    __shared__ float red[4][64];
    __shared__ float redm[4];
    red[g][c] = s;
    if (c == 0) redm[g] = sm;
    __syncthreads();
    if (g == 0) {
        float tot  = red[0][c] + red[1][c] + red[2][c] + red[3][c];
        float totm = redm[0] + redm[1] + redm[2] + redm[3];
        out[(size_t)(b*16 + t)*64 + c] = tot / fmaxf(totm, 1e-6f);
    }
}

// ---------------- host launcher ----------------
extern "C" void kernel_launch(void* const* d_in, const int* in_sizes, int n_in,
                              void* d_out, int out_size, void* d_ws, size_t ws_size,
                              hipStream_t stream)
{
    (void)in_sizes; (void)n_in; (void)out_size;
    if (ws_size < ws_need*sizeof(float)) return;
    const float* frames = (const float*)d_in[0];
    const float* imask  = (const float*)d_in[1];
    const float* Wk   = (const float*)d_in[3];
    const float* Wsh  = (const float*)d_in[4];
    const float* Wse  = (const float*)d_in[5];
    const float* Wf   = (const float*)d_in[6];
    const float* Wv   = (const float*)d_in[7];
    const float* Wh2  = (const float*)d_in[8];
    const float* Whd  = (const float*)d_in[9];
    const float* Wdec = (const float*)d_in[10];
    float* out = (float*)d_out;
    float* ws  = (float*)d_ws;

    bf16_t* wcatT = (bf16_t*)(ws + o_wcatT);
    bf16_t* whfT  = (bf16_t*)(ws + o_whfT);
    bf16_t* wvhT  = (bf16_t*)(ws + o_wvhT);
    float*  wvh1  = ws + o_wvh1;
    bf16_t* WvT   = (bf16_t*)(ws + o_WvT);
    float*  whh   = ws + o_whh;
    bf16_t* wh2T  = (bf16_t*)(ws + o_wh2T);
    bf16_t* keyb  = (bf16_t*)(ws + o_keyb);
    float*  msb   = ws + o_ms;
    bf16_t* qeb   = (bf16_t*)(ws + o_qeb);
    bf16_t* f16b  = (bf16_t*)(ws + o_f16b);
    bf16_t* qfb   = (bf16_t*)(ws + o_qfb);
    bf16_t* kfb   = (bf16_t*)(ws + o_kfb);
    bf16_t* vb    = (bf16_t*)(ws + o_vb);
    bf16_t* vhT   = (bf16_t*)(ws + o_vhT);
    float*  PVp   = ws + o_pv;
    bf16_t* p16b  = (bf16_t*)(ws + o_p16);
    float*  mh    = ws + o_mh;
    float*  hid   = ws + o_hid;
    float*  wmk   = ws + o_wmk;

    k_init<<<2226, 256, 0, stream>>>(Wk, Wsh, Wse, Wf, Wv, Wh2, Whd, Wdec,
                                     wcatT, whfT, WvT, whh, wh2T, out, wvhT, wvh1);
    k_proj<<<dim3(16,32), 512, 0, stream>>>(frames, wcatT, keyb, msb, qeb, f16b);
    k_qf<<<dim3(32,128), dim3(64,8), 0, stream>>>(keyb, qeb, qfb, out);
    k_mask0<<<64, 256, 0, stream>>>(imask, wmk);
    k_prep<<<dim3(32,2), 128, 0, stream>>>(f16b, keyb, msb, wmk, wvhT, wvh1, kfb, vhT, 0, 0);
    k_value<<<dim3(8,16,2), 256, 0, stream>>>(f16b, wmk, WvT, Wv, vb, 0, 0);
    k_hidm<<<dim3(16,2), 256, 0, stream>>>(vb, wh2T, hid, 0, 0);
    k_pre16<<<dim3(16,32), 256, 0, stream>>>(f16b, whfT, p16b);

    for (int ph = 0; ph < 3; ph++) {
        int t0 = 1 + ph*5;
        int ns = (ph + 1)*4;            // N/256 slices: 4, 8, 12
        k_att<<<dim3(16,5,2*ns), 256, 0, stream>>>(qfb, kfb, vhT, PVp, t0);
        k_chain2<<<dim3(256,2), 256, 0, stream>>>(p16b, PVp, whh, hid, wmk, mh, t0, ph, ns);
        if (ph < 2) {
            int tm = t0 + 4, slot = ph + 1;
            k_prep<<<dim3(32,2), 128, 0, stream>>>(f16b, keyb, msb, wmk, wvhT, wvh1, kfb, vhT, tm, slot);
            if (ph == 1) {
                k_value<<<dim3(8,16,2), 256, 0, stream>>>(f16b, wmk, WvT, Wv, vb, tm, slot);
                k_hidm<<<dim3(16,2), 256, 0, stream>>>(vb, wh2T, hid, 2, 1);
            }
        }
    }
    k_feats<<<dim3(15,2), 256, 0, stream>>>(mh, out);
}

// Round 12
// 535.723 us; speedup vs baseline: 1.0420x; 1.0009x over previous
//
#include <hip/hip_runtime.h>
#include <cstdint>

typedef __bf16 bf16_t;
typedef __attribute__((ext_vector_type(8))) __bf16 bf16x8;
typedef __attribute__((ext_vector_type(4))) __bf16 bf16x4;
typedef __attribute__((ext_vector_type(4))) float f32x4;

#define MFMA16(a,b,c) __builtin_amdgcn_mfma_f32_16x16x32_bf16((a),(b),(c),0,0,0)

// ---------------- workspace offsets (float units) ----------------
constexpr size_t PVSTR   = (size_t)2*5*1024*72;  // one N-slice of PV partials
constexpr size_t o_wcatT = 0;                    // bf16 [448][768]
constexpr size_t o_whfT  = o_wcatT + 172032;     // bf16 [128][256]
constexpr size_t o_wvhT  = o_whfT  + 16384;      // bf16 [80][256]  fused Wv@Whv (transposed)
constexpr size_t o_wvh1  = o_wvhT  + 10240;      // f32  [65]  (mask-row of fused weight)
constexpr size_t o_WvT   = o_wvh1  + 80;         // bf16 [512][256]
constexpr size_t o_whh   = o_WvT   + 65536;      // f32  [64][66]
constexpr size_t o_wh2T  = o_whh   + 4224;       // bf16 [64][576]
constexpr size_t o_keyb  = o_wh2T  + 18432;      // bf16 [B*T*1024][64]
constexpr size_t o_ms    = o_keyb  + 1048576;    // f32  [B*T*1024]
constexpr size_t o_qeb   = o_ms    + 32768;      // bf16 [B*T*1024][64]
constexpr size_t o_f16b  = o_qeb   + 1048576;    // bf16 [B*T*1024][256]
constexpr size_t o_qfb   = o_f16b  + 4194304;    // bf16 [B*T*1024][160]
constexpr size_t o_kfb   = o_qfb   + 2621440;    // bf16 [B*3072][160]
constexpr size_t o_vb    = o_kfb   + 491520;     // bf16 [B*3072][512] (slots 0,2 used)
constexpr size_t o_vhT   = o_vb    + 1572864;    // bf16 [B][128][3072] (row65 = ones)
constexpr size_t o_pv    = o_vhT   + 393216;     // f32  [12 slices][B][5][1024][72]
constexpr size_t o_p16   = o_pv    + 12*PVSTR;   // bf16 [B*T*1024][72]
constexpr size_t o_mh    = o_p16   + 1179648;    // f32  [B][15][1024][66]
constexpr size_t o_hid   = o_mh    + 2027520;    // f32  [B][1024][64]
constexpr size_t o_wmk   = o_hid   + 131072;     // f32  [B][1024]
constexpr size_t ws_need = o_wmk   + 2048;

// ---------------- init: weight panels + fused Wv@Whv + zero out[t=0] ----------------
__global__ __launch_bounds__(256)
void k_init(const float* __restrict__ Wk, const float* __restrict__ Wsh,
            const float* __restrict__ Wse, const float* __restrict__ Wf,
            const float* __restrict__ Wv, const float* __restrict__ Wh2,
            const float* __restrict__ Whd, const float* __restrict__ Wdec,
            bf16_t* __restrict__ wcatT, bf16_t* __restrict__ whfT,
            bf16_t* __restrict__ WvT, float* __restrict__ whh,
            bf16_t* __restrict__ wh2T, float* __restrict__ out,
            bf16_t* __restrict__ wvhT, float* __restrict__ wvh1)
{
    int idx = blockIdx.x*256 + threadIdx.x;
    if (idx < 344064) {                       // wcatT[n][k] n<448 k<768
        int n = idx/768, k = idx%768;
        float v = 0.f;
        if (n < 64)       v = Wk[k*64+n];
        else if (n == 64) v = Wsh[k];
        else if (n < 129) v = Wse[k*64+(n-65)];
        else if (n < 385) v = Wf[k*256+(n-129)];
        wcatT[idx] = (bf16_t)v;
        return;
    }
    idx -= 344064;
    if (idx < 32768) {                        // whfT[c][k] c<128 k<256
        int c = idx/256, k = idx%256;
        float v = 0.f;
        if (c < 64) v = Whd[k*64+c]; else if (c == 64) v = Wdec[k];
        whfT[idx] = (bf16_t)v;
        return;
    }
    idx -= 32768;
    if (idx < 131072) {                       // WvT[n][k] n<512 k<256
        int n = idx/256, k = idx%256;
        WvT[idx] = (bf16_t)Wv[k*512+n];
        return;
    }
    idx -= 131072;
    if (idx < 4224) {                         // whh[k][c] (stride 66), c<65 real
        int k = idx/66, c = idx%66;
        float v = 0.f;
        if (c < 64) v = Whd[(768+k)*64+c]; else if (c == 64) v = Wdec[768+k];
        whh[idx] = v;
        return;
    }
    idx -= 4224;
    if (idx < 36864) {                        // wh2T[c][k] c<64 k<576
        int c = idx/576, k = idx%576;
        wh2T[idx] = (bf16_t)Wh2[k*64+c];
        return;
    }
    idx -= 36864;
    if (idx < 128) {                          // zero out[t=0] (feat0 atomics)
        int b = idx>>6, c = idx&63;
        out[(size_t)b*1024 + c] = 0.f;
        return;
    }
    idx -= 128;
    if (idx < 20480) {                        // wvhT[c][k] = (Wv@whv)[k][c]
        int k = idx / 80, c = idx % 80;
        float s = 0.f;
        if (c < 65) {
            for (int j = 0; j < 512; j++) {
                float hv = (c < 64) ? Whd[(256+j)*64 + c] : Wdec[256 + j];
                s = fmaf(Wv[k*512 + j], hv, s);
            }
        }
        wvhT[(size_t)c*256 + k] = (bf16_t)s;
        return;
    }
    idx -= 20480;
    if (idx < 65) {                           // mask-row of fused weight
        int c = idx;
        float s = 0.f;
        for (int j = 0; j < 512; j++) {
            float hv = (c < 64) ? Whd[(256+j)*64 + c] : Wdec[256 + j];
            s = fmaf(Wv[256*512 + j], hv, s);
        }
        wvh1[c] = s;
    }
}

// ---------------- projection GEMM v4: 64x448 tile, 8 waves, LDS-staged A (once), ----
// contiguous global loads, 2-deep reg prefetch, 1 barrier/chunk, XOR-swizzled LDS.
// grid (16, 32), block 512. waves: wp = w>>2 (p half), wn = w&3 (n quarter).
__global__ __launch_bounds__(512)
void k_proj(const float* __restrict__ frames, const bf16_t* __restrict__ wcatT,
            bf16_t* __restrict__ keyb, float* __restrict__ msb,
            bf16_t* __restrict__ qeb, bf16_t* __restrict__ f16b)
{
    const int bx = blockIdx.x, bt = blockIdx.y;
    const int p0 = bx*64;
    const int tid = threadIdx.x, lane = tid & 63, w = tid >> 6;
    const int wp = w >> 2, wn = w & 3;
    const int l15 = lane & 15, l4 = lane >> 4;
    __shared__ __align__(16) bf16_t Al[2][4][512];     // [buf][imgrow r][512 bf16] = 8KB
    f32x4 acc[2][7] = {};
    const float* fb = frames + (size_t)bt*786432;

    // loader: thread -> r = tid>>7 in [0,4), 4 consecutive floats at (tid&127)*4
    const int lr = tid >> 7, lxb = (tid & 127)*8;       // lxb = byte offset (bf16) in row
    const float* gbase = fb + (size_t)((bx*2 + (lr>>1))*16 + (lr&1))*512 + (tid & 127)*4;
    const int wbyte = lr*1024 + (lxb ^ (((lxb>>7)&3)<<4));
    // frag read: r = wp*2 + (l4>>1); inner byte = l15*32 + (l4&1)*16 (+ fi*512)
    const int rb_in = l15*32 + (l4&1)*16;
    const int rbyte = (wp*2 + (l4>>1))*1024 + (rb_in ^ (((rb_in>>7)&3)<<4));
    char* lds = (char*)&Al[0][0][0];

    #define PLOAD(dst, kc) dst = *(const float4*)(gbase + (size_t)((kc)>>3)*262144 + (size_t)(((kc)&7)*2)*512)
    #define PSTORE(buf, v) { bf16x4 pk; pk[0]=(bf16_t)(v).x; pk[1]=(bf16_t)(v).y; \
        pk[2]=(bf16_t)(v).z; pk[3]=(bf16_t)(v).w; \
        *(bf16x4*)(lds + (buf)*4096 + wbyte) = pk; }

    float4 va, vb;
    PLOAD(va, 0); PLOAD(vb, 1);
    PSTORE(0, va); PLOAD(va, 2);
    PSTORE(1, vb); PLOAD(vb, 3);
    __syncthreads();

    for (int kc = 0; kc < 24; kc++) {
        const int buf = kc & 1;
        bf16x8 af0 = *(const bf16x8*)(lds + buf*4096 + rbyte);
        bf16x8 af1 = *(const bf16x8*)(lds + buf*4096 + rbyte + 512);
        __syncthreads();                       // reads of buf done; prev stores visible
        if (kc < 22) {
            if (buf == 0) { PSTORE(0, va); if (kc < 20) PLOAD(va, kc+4); }
            else          { PSTORE(1, vb); if (kc < 20) PLOAD(vb, kc+4); }
        }
        #pragma unroll
        for (int fj = 0; fj < 7; fj++) {
            int n = wn*112 + fj*16 + l15;
            bf16x8 bv = *(const bf16x8*)(wcatT + (size_t)n*768 + kc*32 + l4*8);
            acc[0][fj] = MFMA16(af0, bv, acc[0][fj]);
            acc[1][fj] = MFMA16(af1, bv, acc[1][fj]);
        }
    }
    #undef PLOAD
    #undef PSTORE

    #pragma unroll
    for (int fi = 0; fi < 2; fi++)
    #pragma unroll
    for (int fj = 0; fj < 7; fj++) {
        int nn = wn*112 + fj*16 + l15;
        #pragma unroll
        for (int rr = 0; rr < 4; rr++) {
            int pp = p0 + wp*32 + fi*16 + l4*4 + rr;
            float v = acc[fi][fj][rr];
            size_t rowb = (size_t)bt*1024 + pp;
            if (nn < 64)       keyb[rowb*64 + nn] = (bf16_t)v;
            else if (nn == 64) msb[rowb] = v*v + 1.f;
            else if (nn < 129) qeb[rowb*64 + (nn-65)] = (bf16_t)(1.f/(1.f+expf(-v)));
            else if (nn < 385) f16b[rowb*256 + (nn-129)] = (bf16_t)v;
        }
    }
}

// ---------------- Qfeat + fused feat0 partial reduce ----------------
// grid (32 bt, 128), block (64,8)
__global__ __launch_bounds__(512)
void k_qf(const bf16_t* __restrict__ keyb, const bf16_t* __restrict__ qeb,
          bf16_t* __restrict__ qfb, float* __restrict__ out)
{
    int bt = blockIdx.x;
    int p = blockIdx.y*8 + threadIdx.y;
    int c = threadIdx.x;
    size_t rowb = (size_t)bt*1024 + p;
    float qk = (float)keyb[rowb*64 + c];
    float qv = (float)qeb[rowb*64 + c];
    float bsq = qv*qk*qk;
    #pragma unroll
    for (int off = 32; off; off >>= 1) bsq += __shfl_xor(bsq, off);
    bf16_t* q = qfb + rowb*160;
    q[c]      = (bf16_t)(qv*qk);
    q[64 + c] = (bf16_t)qv;
    if (c == 0) q[128] = (bf16_t)bsq;
    if (c < 31) q[129 + c] = (bf16_t)0.f;
    if ((bt & 15) == 0) {                      // t==0: feat0 = mean over p of key
        __shared__ float fred[64];
        if (threadIdx.y == 0) fred[c] = 0.f;
        __syncthreads();
        atomicAdd(&fred[c], qk);
        __syncthreads();
        if (threadIdx.y == 0)
            atomicAdd(&out[(size_t)(bt >> 4)*1024 + c], fred[c]*(1.f/1024.f));
    }
}

// ---------------- t=0 mask: aggregate + 16x16 avg-pool (coalesced) ----------------
__global__ __launch_bounds__(256)
void k_mask0(const float* __restrict__ im, float* __restrict__ wmask)
{
    int blk = blockIdx.x;
    int b = blk >> 5, i = blk & 31;
    int tid = threadIdx.x;
    int xq = tid & 127, yh = tid >> 7;
    const float* base = im + (size_t)b*262144 + (size_t)(i*16)*512;
    float s = 0.f;
    for (int yy = 0; yy < 8; yy++) {
        int y = yy*2 + yh;
        float4 v = *(const float4*)(base + (size_t)y*512 + xq*4);
        float e[4] = {v.x, v.y, v.z, v.w};
        #pragma unroll
        for (int u = 0; u < 4; u++) {
            float pc = fminf(fmaxf(e[u],      1e-7f), 1.f-1e-7f);
            float qc = fminf(fmaxf(1.f-e[u],  1e-7f), 1.f-1e-7f);
            s += pc*pc/(pc*pc + qc*qc);
        }
    }
    __shared__ float red[32];
    if (tid < 32) red[tid] = 0.f;
    __syncthreads();
    atomicAdd(&red[xq >> 2], s);
    __syncthreads();
    if (tid < 32) wmask[b*1024 + i*32 + tid] = red[tid]*(1.f/256.f);
}

// ---------------- per-slot prep: kf rows + vhT GEMM ----------------
// grid (32, 2), block 128 (2 waves, 32 rows per block)
__global__ __launch_bounds__(128)
void k_prep(const bf16_t* __restrict__ f16b, const bf16_t* __restrict__ keyb,
            const float* __restrict__ msb, const float* __restrict__ wmk,
            const bf16_t* __restrict__ wvhT, const float* __restrict__ wvh1,
            bf16_t* __restrict__ kfb, bf16_t* __restrict__ vhT, int tm, int slot)
{
    int b = blockIdx.y, n0 = blockIdx.x*32;
    int tid = threadIdx.x, lane = tid & 63, w = tid >> 6;
    // ---- kf fill ----
    {
        int row = n0 + (tid >> 2), q = tid & 3;
        size_t rowb = (size_t)(b*16 + tm)*1024 + row;
        float m = msb[rowb];
        bf16_t* kr = kfb + ((size_t)b*3072 + slot*1024 + row)*160;
        bf16x8 k0v = *(const bf16x8*)(keyb + rowb*64 + q*16);
        bf16x8 k1v = *(const bf16x8*)(keyb + rowb*64 + q*16 + 8);
        bf16x8 o0, o1, s0, s1;
        #pragma unroll
        for (int u = 0; u < 8; u++) {
            float mk0 = (float)k0v[u], mk1 = (float)k1v[u];
            o0[u] = (bf16_t)( m*mk0*0.25f);       o1[u] = (bf16_t)( m*mk1*0.25f);
            s0[u] = (bf16_t)(-m*mk0*mk0*0.125f);  s1[u] = (bf16_t)(-m*mk1*mk1*0.125f);
        }
        *(bf16x8*)(kr + q*16)      = o0;  *(bf16x8*)(kr + q*16 + 8)      = o1;
        *(bf16x8*)(kr + 64 + q*16) = s0;  *(bf16x8*)(kr + 64 + q*16 + 8) = s1;
        if (q == 0) kr[128] = (bf16_t)(-m*0.125f);
        else if (q == 1) { for (int u = 0; u < 15; u++) kr[129+u] = (bf16_t)0.f; }
        else if (q == 2) { for (int u = 0; u < 16; u++) kr[144+u] = (bf16_t)0.f; }
    }
    // ---- vh GEMM: 32 n-rows x 80 c, K=256 ----
    int l15 = lane & 15, l4 = lane >> 4;
    const bf16_t* A = f16b + ((size_t)(b*16 + tm)*1024 + n0 + w*16 + l15)*256;
    f32x4 acc[5] = {};
    #pragma unroll
    for (int ks = 0; ks < 8; ks++) {
        bf16x8 a0 = *(const bf16x8*)(A + ks*32 + l4*8);
        #pragma unroll
        for (int cf = 0; cf < 5; cf++) {
            bf16x8 bv = *(const bf16x8*)(wvhT + (size_t)(cf*16 + l15)*256 + ks*32 + l4*8);
            acc[cf] = MFMA16(a0, bv, acc[cf]);
        }
    }
    #pragma unroll
    for (int cf = 0; cf < 5; cf++) {
        int cc = cf*16 + l15;
        float w1 = (cc < 65) ? wvh1[cc] : 0.f;
        #pragma unroll
        for (int rr = 0; rr < 4; rr++) {
            int p = n0 + w*16 + l4*4 + rr;
            float val;
            if (cc < 65)      val = acc[cf][rr] + wmk[b*1024 + p]*w1;
            else              val = (cc == 65) ? 1.f : 0.f;
            vhT[(size_t)b*393216 + (size_t)cc*3072 + slot*1024 + p] = (bf16_t)val;
        }
    }
}

// ---------------- value (MFMA): V = f16 @ Wv[0:256] + wmask*Wv[256] (slots 0,2) ----------------
__global__ __launch_bounds__(256)
void k_value(const bf16_t* __restrict__ f16b, const float* __restrict__ wmk,
             const bf16_t* __restrict__ WvT, const float* __restrict__ Wv,
             bf16_t* __restrict__ vb, int t, int slot)
{
    int b = blockIdx.z;
    int n0 = blockIdx.x*64, p0 = blockIdx.y*64;
    const int tid = threadIdx.x, lane = tid & 63, w = tid >> 6;
    const int wr = w >> 1, wc = w & 1, l15 = lane & 15, l4 = lane >> 4;
    const bf16_t* A = f16b + ((size_t)(b*16 + t)*1024 + p0)*256;
    f32x4 acc[2][2] = {};
    int ar = wr*32 + l15, bc = n0 + wc*32 + l15, koff = l4*8;
    #pragma unroll
    for (int ks = 0; ks < 8; ks++) {
        bf16x8 a0 = *(const bf16x8*)(A + (size_t)ar*256 + ks*32 + koff);
        bf16x8 a1 = *(const bf16x8*)(A + (size_t)(ar+16)*256 + ks*32 + koff);
        bf16x8 b0 = *(const bf16x8*)(WvT + (size_t)bc*256 + ks*32 + koff);
        bf16x8 b1 = *(const bf16x8*)(WvT + (size_t)(bc+16)*256 + ks*32 + koff);
        acc[0][0] = MFMA16(a0, b0, acc[0][0]);
        acc[0][1] = MFMA16(a0, b1, acc[0][1]);
        acc[1][0] = MFMA16(a1, b0, acc[1][0]);
        acc[1][1] = MFMA16(a1, b1, acc[1][1]);
    }
    #pragma unroll
    for (int fi = 0; fi < 2; fi++)
    #pragma unroll
    for (int fj = 0; fj < 2; fj++) {
        int nn = n0 + wc*32 + fj*16 + l15;
        float wvl = Wv[131072 + nn];
        #pragma unroll
        for (int rr = 0; rr < 4; rr++) {
            int pp = p0 + wr*32 + fi*16 + l4*4 + rr;
            float wm = wmk[b*1024 + pp];
            vb[((size_t)b*3072 + slot*1024 + pp)*512 + nn] = (bf16_t)(acc[fi][fj][rr] + wm*wvl);
        }
    }
}

// ---------------- pre16 (MFMA): f16 @ [Whd_lo|Wdec_lo] -> [p][65] ----------------
__global__ __launch_bounds__(256)
void k_pre16(const bf16_t* __restrict__ f16b, const bf16_t* __restrict__ whfT,
             bf16_t* __restrict__ p16b)
{
    int bt = blockIdx.y;
    int p0 = blockIdx.x*64;
    const int tid = threadIdx.x, lane = tid & 63, w = tid >> 6;
    const int wr = w >> 1, wc = w & 1, l15 = lane & 15, l4 = lane >> 4;
    const bf16_t* A = f16b + ((size_t)bt*1024 + p0)*256;
    f32x4 acc[2][4] = {};
    int ar = wr*32 + l15, koff = l4*8;
    #pragma unroll
    for (int ks = 0; ks < 8; ks++) {
        bf16x8 a0 = *(const bf16x8*)(A + (size_t)ar*256 + ks*32 + koff);
        bf16x8 a1 = *(const bf16x8*)(A + (size_t)(ar+16)*256 + ks*32 + koff);
        #pragma unroll
        for (int fj = 0; fj < 4; fj++) {
            int cc = wc*64 + fj*16 + l15;
            bf16x8 bv = *(const bf16x8*)(whfT + (size_t)cc*256 + ks*32 + koff);
            acc[0][fj] = MFMA16(a0, bv, acc[0][fj]);
            acc[1][fj] = MFMA16(a1, bv, acc[1][fj]);
        }
    }
    #pragma unroll
    for (int fi = 0; fi < 2; fi++)
    #pragma unroll
    for (int fj = 0; fj < 4; fj++) {
        int cc = wc*64 + fj*16 + l15;
        if (cc < 65) {
            #pragma unroll
            for (int rr = 0; rr < 4; rr++) {
                int pp = p0 + wr*32 + fi*16 + l4*4 + rr;
                p16b[((size_t)bt*1024 + pp)*72 + cc] = (bf16_t)acc[fi][fj][rr];
            }
        }
    }
}

// ---------------- split-N attention: exp(S)·Vh partials (sim<=0, no max/sum) ----------------
__global__ __launch_bounds__(256)
void k_att(const bf16_t* __restrict__ qfb, const bf16_t* __restrict__ kfb,
           const bf16_t* __restrict__ vhT, float* __restrict__ PVp, int t0)
{
    int b = blockIdx.z & 1, sl = blockIdx.z >> 1;
    int ts = blockIdx.y, t = t0 + ts, p0 = blockIdx.x*64;
    int n_base = sl*256;
    int tid = threadIdx.x, lane = tid & 63, w = tid >> 6;
    int l15 = lane & 15, l4 = lane >> 4;
    __shared__ __align__(16) bf16_t P_lds[4][16][72];

    const bf16_t* Q = qfb + ((size_t)(b*16 + t)*1024 + p0 + w*16 + l15)*160 + l4*8;
    bf16x8 aq[5];
    #pragma unroll
    for (int kc = 0; kc < 5; kc++) aq[kc] = *(const bf16x8*)(Q + kc*32);

    const bf16_t* K  = kfb + ((size_t)b*3072 + n_base)*160;
    const bf16_t* Vh = vhT + (size_t)b*393216 + n_base;
    f32x4 o[5] = {};

    for (int n0 = 0; n0 < 256; n0 += 64) {
        f32x4 s[4] = {};
        #pragma unroll
        for (int kc = 0; kc < 5; kc++) {
            #pragma unroll
            for (int nf = 0; nf < 4; nf++) {
                bf16x8 bk = *(const bf16x8*)(K + (size_t)(n0 + nf*16 + l15)*160 + kc*32 + l4*8);
                s[nf] = MFMA16(aq[kc], bk, s[nf]);
            }
        }
        #pragma unroll
        for (int nf = 0; nf < 4; nf++) {
            #pragma unroll
            for (int rr = 0; rr < 4; rr++) {
                float pe = __expf(s[nf][rr]);
                P_lds[w][l4*4 + rr][nf*16 + l15] = (bf16_t)pe;
            }
        }
        #pragma unroll
        for (int kc2 = 0; kc2 < 2; kc2++) {
            bf16x8 ap = *(const bf16x8*)&P_lds[w][l15][kc2*32 + l4*8];
            #pragma unroll
            for (int cf = 0; cf < 5; cf++) {
                bf16x8 bv = *(const bf16x8*)(Vh + (size_t)(cf*16 + l15)*3072 + n0 + kc2*32 + l4*8);
                o[cf] = MFMA16(ap, bv, o[cf]);
            }
        }
    }
    float* O = PVp + (size_t)sl*PVSTR + ((size_t)((b*5 + ts)*1024) + p0 + w*16)*72;
    #pragma unroll
    for (int cf = 0; cf < 5; cf++) {
        int cc = cf*16 + l15;
        if (cc < 66) {
            #pragma unroll
            for (int rr = 0; rr < 4; rr++)
                O[(size_t)(l4*4 + rr)*72 + cc] = o[cf][rr];
        }
    }
}

// ---------------- sequential 5-step chain; sums PV slices, divides by col65 ----------------
__global__ __launch_bounds__(256)
void k_chain2(const bf16_t* __restrict__ p16b, const float* __restrict__ PVp,
              const float* __restrict__ whhbuf, float* __restrict__ hidden,
              float* __restrict__ wmk, float* __restrict__ mh, int t0, int ph, int ns)
{
    int b = blockIdx.y;
    int tid = threadIdx.x, lane = tid & 63, w = tid >> 6;
    int p = blockIdx.x*4 + w;
    __shared__ float whh_s[64][66];
    __shared__ float hid_s[4][64];
    for (int idx = tid; idx < 64*66; idx += 256) whh_s[idx/66][idx%66] = whhbuf[idx];
    float h = hidden[((size_t)b*1024 + p)*64 + lane];
    hid_s[w][lane] = h;
    __syncthreads();
    float wd = whh_s[lane][64];
    for (int ts = 0; ts < 5; ts++) {
        int t = t0 + ts;
        size_t r16 = ((size_t)(b*16 + t)*1024 + p)*72;
        size_t rpv = ((size_t)((b*5 + ts)*1024) + p)*72;
        float pvc = 0.f, pv64 = 0.f, pv65 = 0.f;
        for (int s2 = 0; s2 < ns; s2++) {
            const float* bp = PVp + (size_t)s2*PVSTR + rpv;
            pvc  += bp[lane];
            pv64 += bp[64];
            pv65 += bp[65];
        }
        float rinv  = 1.f/pv65;
        float pre   = (float)p16b[r16 + lane] + pvc*rinv;
        float fgpre = (float)p16b[r16 + 64]   + pv64*rinv;
        float s = pre;
        #pragma unroll 8
        for (int k = 0; k < 64; k++) s += hid_s[w][k]*whh_s[k][lane];
        float hl = tanhf(s);
        float fgs = hl*wd;
        #pragma unroll
        for (int off = 1; off < 64; off <<= 1) fgs += __shfl_xor(fgs, off);
        float fg = fgpre + fgs;
        float m = 1.f/(1.f+expf(-fg));
        size_t rmh = ((size_t)(b*15 + ph*5 + ts)*1024 + p)*66;
        mh[rmh + lane] = m*hl;
        if (lane == 0) mh[rmh + 64] = m;
        if (ts == 4 && lane == 0) wmk[b*1024 + p] = m;
        h = hl;
        __syncthreads();
        hid_s[w][lane] = h;
        __syncthreads();
    }
    hidden[((size_t)b*1024 + p)*64 + lane] = h;
}

// ---------------- hidden update (MFMA): tanh([V | hid?] @ Wh2) ----------------
__global__ __launch_bounds__(256)
void k_hidm(const bf16_t* __restrict__ vb, const bf16_t* __restrict__ wh2T,
            float* __restrict__ hidden, int vslot, int has_h)
{
    int b = blockIdx.y, p0 = blockIdx.x*64;
    int tid = threadIdx.x, lane = tid & 63, w = tid >> 6;
    int l15 = lane & 15, l4 = lane >> 4;
    int arow = p0 + w*16 + l15;
    const bf16_t* A = vb + ((size_t)b*3072 + vslot*1024 + arow)*512;
    const float* Hp = hidden + ((size_t)b*1024 + arow)*64;
    f32x4 acc[4] = {};
    int kiters = has_h ? 18 : 16;
    for (int ks = 0; ks < kiters; ks++) {
        bf16x8 a0;
        if (ks < 16) a0 = *(const bf16x8*)(A + ks*32 + l4*8);
        else {
            int ko = (ks-16)*32 + l4*8;
            float4 h0 = *(const float4*)(Hp + ko);
            float4 h1 = *(const float4*)(Hp + ko + 4);
            a0[0]=(bf16_t)h0.x; a0[1]=(bf16_t)h0.y; a0[2]=(bf16_t)h0.z; a0[3]=(bf16_t)h0.w;
            a0[4]=(bf16_t)h1.x; a0[5]=(bf16_t)h1.y; a0[6]=(bf16_t)h1.z; a0[7]=(bf16_t)h1.w;
        }
        #pragma unroll
        for (int cf = 0; cf < 4; cf++) {
            bf16x8 bv = *(const bf16x8*)(wh2T + (size_t)(cf*16 + l15)*576 + ks*32 + l4*8);
            acc[cf] = MFMA16(a0, bv, acc[cf]);
        }
    }
    #pragma unroll
    for (int cf = 0; cf < 4; cf++) {
        int cc = cf*16 + l15;
        #pragma unroll
        for (int rr = 0; rr < 4; rr++) {
            int p = p0 + w*16 + l4*4 + rr;
            hidden[((size_t)b*1024 + p)*64 + cc] = tanhf(acc[cf][rr]);
        }
    }
}

// ---------------- feats t=1..15: weighted mean reduce ----------------
__global__ __launch_bounds__(256)
void k_feats(const float* __restrict__ mh, float* __restrict__ out)
{
    int slot = blockIdx.x, b = blockIdx.y, t = slot + 1;
    int tid = threadIdx.x, c = tid & 63, g = tid >> 6;
    const float* base = mh + (size_t)(b*15 + slot)*1024*66;
    float s = 0.f, sm = 0.f;
    for (int p = g; p < 1024; p += 4) {
        s += base[(size_t)p*66 + c];
        if (c == 0) sm += base[(size_t)p*66 + 64];
    }
    __shared__ float red[4][64];
    __shared__ float redm[4];
    red[g][c] = s;
    if (c == 0) redm[g] = sm;
    __syncthreads();
    if (g == 0) {
        float tot  = red[0][c] + red[1][c] + red[2][c] + red[3][c];
        float totm = redm[0] + redm[1] + redm[2] + redm[3];
        out[(size_t)(b*16 + t)*64 + c] = tot / fmaxf(totm, 1e-6f);
    }
}

// ---------------- host launcher ----------------
extern "C" void kernel_launch(void* const* d_in, const int* in_sizes, int n_in,
                              void* d_out, int out_size, void* d_ws, size_t ws_size,
                              hipStream_t stream)
{
    (void)in_sizes; (void)n_in; (void)out_size;
    if (ws_size < ws_need*sizeof(float)) return;
    const float* frames = (const float*)d_in[0];
    const float* imask  = (const float*)d_in[1];
    const float* Wk   = (const float*)d_in[3];
    const float* Wsh  = (const float*)d_in[4];
    const float* Wse  = (const float*)d_in[5];
    const float* Wf   = (const float*)d_in[6];
    const float* Wv   = (const float*)d_in[7];
    const float* Wh2  = (const float*)d_in[8];
    const float* Whd  = (const float*)d_in[9];
    const float* Wdec = (const float*)d_in[10];
    float* out = (float*)d_out;
    float* ws  = (float*)d_ws;

    bf16_t* wcatT = (bf16_t*)(ws + o_wcatT);
    bf16_t* whfT  = (bf16_t*)(ws + o_whfT);
    bf16_t* wvhT  = (bf16_t*)(ws + o_wvhT);
    float*  wvh1  = ws + o_wvh1;
    bf16_t* WvT   = (bf16_t*)(ws + o_WvT);
    float*  whh   = ws + o_whh;
    bf16_t* wh2T  = (bf16_t*)(ws + o_wh2T);
    bf16_t* keyb  = (bf16_t*)(ws + o_keyb);
    float*  msb   = ws + o_ms;
    bf16_t* qeb   = (bf16_t*)(ws + o_qeb);
    bf16_t* f16b  = (bf16_t*)(ws + o_f16b);
    bf16_t* qfb   = (bf16_t*)(ws + o_qfb);
    bf16_t* kfb   = (bf16_t*)(ws + o_kfb);
    bf16_t* vb    = (bf16_t*)(ws + o_vb);
    bf16_t* vhT   = (bf16_t*)(ws + o_vhT);
    float*  PVp   = ws + o_pv;
    bf16_t* p16b  = (bf16_t*)(ws + o_p16);
    float*  mh    = ws + o_mh;
    float*  hid   = ws + o_hid;
    float*  wmk   = ws + o_wmk;

    k_init<<<2226, 256, 0, stream>>>(Wk, Wsh, Wse, Wf, Wv, Wh2, Whd, Wdec,
                                     wcatT, whfT, WvT, whh, wh2T, out, wvhT, wvh1);
    k_proj<<<dim3(16,32), 512, 0, stream>>>(frames, wcatT, keyb, msb, qeb, f16b);
    k_qf<<<dim3(32,128), dim3(64,8), 0, stream>>>(keyb, qeb, qfb, out);
    k_mask0<<<64, 256, 0, stream>>>(imask, wmk);
    k_prep<<<dim3(32,2), 128, 0, stream>>>(f16b, keyb, msb, wmk, wvhT, wvh1, kfb, vhT, 0, 0);
    k_value<<<dim3(8,16,2), 256, 0, stream>>>(f16b, wmk, WvT, Wv, vb, 0, 0);
    k_hidm<<<dim3(16,2), 256, 0, stream>>>(vb, wh2T, hid, 0, 0);
    k_pre16<<<dim3(16,32), 256, 0, stream>>>(f16b, whfT, p16b);

    for (int ph = 0; ph < 3; ph++) {
        int t0 = 1 + ph*5;
        int ns = (ph + 1)*4;            // N/256 slices: 4, 8, 12
        k_att<<<dim3(16,5,2*ns), 256, 0, stream>>>(qfb, kfb, vhT, PVp, t0);
        k_chain2<<<dim3(256,2), 256, 0, stream>>>(p16b, PVp, whh, hid, wmk, mh, t0, ph, ns);
        if (ph < 2) {
            int tm = t0 + 4, slot = ph + 1;
            k_prep<<<dim3(32,2), 128, 0, stream>>>(f16b, keyb, msb, wmk, wvhT, wvh1, kfb, vhT, tm, slot);
            if (ph == 1) {
                k_value<<<dim3(8,16,2), 256, 0, stream>>>(f16b, wmk, WvT, Wv, vb, tm, slot);
                k_hidm<<<dim3(16,2), 256, 0, stream>>>(vb, wh2T, hid, 2, 1);
            }
        }
    }
    k_feats<<<dim3(15,2), 256, 0, stream>>>(mh, out);
}

// Round 13
// 535.105 us; speedup vs baseline: 1.0432x; 1.0012x over previous
//
#include <hip/hip_runtime.h>
#include <cstdint>

typedef __bf16 bf16_t;
typedef __attribute__((ext_vector_type(8))) __bf16 bf16x8;
typedef __attribute__((ext_vector_type(4))) __bf16 bf16x4;
typedef __attribute__((ext_vector_type(4))) float f32x4;

#define MFMA16(a,b,c) __builtin_amdgcn_mfma_f32_16x16x32_bf16((a),(b),(c),0,0,0)

// ---------------- workspace offsets (float units) ----------------
constexpr size_t PVSTR   = (size_t)2*5*1024*72;  // one N-slice of PV partials
constexpr size_t o_wcatT = 0;                    // bf16 [448][768]
constexpr size_t o_whfT  = o_wcatT + 172032;     // bf16 [128][256]
constexpr size_t o_wvhT  = o_whfT  + 16384;      // bf16 [80][256]  fused Wv@Whv (transposed)
constexpr size_t o_wvh1  = o_wvhT  + 10240;      // f32  [65]  (mask-row of fused weight)
constexpr size_t o_WvT   = o_wvh1  + 80;         // bf16 [512][256]
constexpr size_t o_whh   = o_WvT   + 65536;      // f32  [64][66]
constexpr size_t o_wh2T  = o_whh   + 4224;       // bf16 [64][576]
constexpr size_t o_keyb  = o_wh2T  + 18432;      // bf16 [B*T*1024][64]
constexpr size_t o_ms    = o_keyb  + 1048576;    // f32  [B*T*1024]
constexpr size_t o_qeb   = o_ms    + 32768;      // bf16 [B*T*1024][64]
constexpr size_t o_f16b  = o_qeb   + 1048576;    // bf16 [B*T*1024][256]
constexpr size_t o_qfb   = o_f16b  + 4194304;    // bf16 [B*T*1024][160]
constexpr size_t o_kfb   = o_qfb   + 2621440;    // bf16 [B*3072][160]
constexpr size_t o_vb    = o_kfb   + 491520;     // bf16 [B*3072][512] (slots 0,2 used)
constexpr size_t o_vhT   = o_vb    + 1572864;    // bf16 [B][128][3072] (row65 = ones)
constexpr size_t o_pv    = o_vhT   + 393216;     // f32  [12 slices][B][5][1024][72]
constexpr size_t o_p16   = o_pv    + 12*PVSTR;   // bf16 [B*T*1024][72]
constexpr size_t o_mh    = o_p16   + 1179648;    // f32  [B][15][1024][66]
constexpr size_t o_hid   = o_mh    + 2027520;    // f32  [B][1024][64]
constexpr size_t o_wmk   = o_hid   + 131072;     // f32  [B][1024]
constexpr size_t ws_need = o_wmk   + 2048;

// ---------------- init: weight panels + fused Wv@Whv + zero out[t=0] ----------------
__global__ __launch_bounds__(256)
void k_init(const float* __restrict__ Wk, const float* __restrict__ Wsh,
            const float* __restrict__ Wse, const float* __restrict__ Wf,
            const float* __restrict__ Wv, const float* __restrict__ Wh2,
            const float* __restrict__ Whd, const float* __restrict__ Wdec,
            bf16_t* __restrict__ wcatT, bf16_t* __restrict__ whfT,
            bf16_t* __restrict__ WvT, float* __restrict__ whh,
            bf16_t* __restrict__ wh2T, float* __restrict__ out,
            bf16_t* __restrict__ wvhT, float* __restrict__ wvh1)
{
    int idx = blockIdx.x*256 + threadIdx.x;
    if (idx < 344064) {                       // wcatT[n][k] n<448 k<768
        int n = idx/768, k = idx%768;
        float v = 0.f;
        if (n < 64)       v = Wk[k*64+n];
        else if (n == 64) v = Wsh[k];
        else if (n < 129) v = Wse[k*64+(n-65)];
        else if (n < 385) v = Wf[k*256+(n-129)];
        wcatT[idx] = (bf16_t)v;
        return;
    }
    idx -= 344064;
    if (idx < 32768) {                        // whfT[c][k] c<128 k<256
        int c = idx/256, k = idx%256;
        float v = 0.f;
        if (c < 64) v = Whd[k*64+c]; else if (c == 64) v = Wdec[k];
        whfT[idx] = (bf16_t)v;
        return;
    }
    idx -= 32768;
    if (idx < 131072) {                       // WvT[n][k] n<512 k<256
        int n = idx/256, k = idx%256;
        WvT[idx] = (bf16_t)Wv[k*512+n];
        return;
    }
    idx -= 131072;
    if (idx < 4224) {                         // whh[k][c] (stride 66), c<65 real
        int k = idx/66, c = idx%66;
        float v = 0.f;
        if (c < 64) v = Whd[(768+k)*64+c]; else if (c == 64) v = Wdec[768+k];
        whh[idx] = v;
        return;
    }
    idx -= 4224;
    if (idx < 36864) {                        // wh2T[c][k] c<64 k<576
        int c = idx/576, k = idx%576;
        wh2T[idx] = (bf16_t)Wh2[k*64+c];
        return;
    }
    idx -= 36864;
    if (idx < 128) {                          // zero out[t=0] (feat0 atomics)
        int b = idx>>6, c = idx&63;
        out[(size_t)b*1024 + c] = 0.f;
        return;
    }
    idx -= 128;
    if (idx < 20480) {                        // wvhT[c][k] = (Wv@whv)[k][c]
        int k = idx / 80, c = idx % 80;
        float s = 0.f;
        if (c < 65) {
            for (int j = 0; j < 512; j++) {
                float hv = (c < 64) ? Whd[(256+j)*64 + c] : Wdec[256 + j];
                s = fmaf(Wv[k*512 + j], hv, s);
            }
        }
        wvhT[(size_t)c*256 + k] = (bf16_t)s;
        return;
    }
    idx -= 20480;
    if (idx < 65) {                           // mask-row of fused weight
        int c = idx;
        float s = 0.f;
        for (int j = 0; j < 512; j++) {
            float hv = (c < 64) ? Whd[(256+j)*64 + c] : Wdec[256 + j];
            s = fmaf(Wv[256*512 + j], hv, s);
        }
        wvh1[c] = s;
    }
}

// ---------------- projection GEMM v5: raw barriers, prefetch stays in flight --------
// Same 64x448 tile / LDS staging as v4, but __syncthreads() (which drains vmcnt(0)
// and kills the 2-deep global prefetch) is replaced by s_waitcnt lgkmcnt(0) +
// raw s_barrier: LDS ordering is preserved, global loads remain outstanding.
// grid (16, 32), block 512.
__global__ __launch_bounds__(512)
void k_proj(const float* __restrict__ frames, const bf16_t* __restrict__ wcatT,
            bf16_t* __restrict__ keyb, float* __restrict__ msb,
            bf16_t* __restrict__ qeb, bf16_t* __restrict__ f16b)
{
    const int bx = blockIdx.x, bt = blockIdx.y;
    const int p0 = bx*64;
    const int tid = threadIdx.x, lane = tid & 63, w = tid >> 6;
    const int wp = w >> 2, wn = w & 3;
    const int l15 = lane & 15, l4 = lane >> 4;
    __shared__ __align__(16) bf16_t Al[2][4][512];     // [buf][imgrow r][512 bf16] = 8KB
    f32x4 acc[2][7] = {};
    const float* fb = frames + (size_t)bt*786432;

    const int lr = tid >> 7, lxb = (tid & 127)*8;
    const float* gbase = fb + (size_t)((bx*2 + (lr>>1))*16 + (lr&1))*512 + (tid & 127)*4;
    const int wbyte = lr*1024 + (lxb ^ (((lxb>>7)&3)<<4));
    const int rb_in = l15*32 + (l4&1)*16;
    const int rbyte = (wp*2 + (l4>>1))*1024 + (rb_in ^ (((rb_in>>7)&3)<<4));
    char* lds = (char*)&Al[0][0][0];

    #define PLOAD(dst, kc) dst = *(const float4*)(gbase + (size_t)((kc)>>3)*262144 + (size_t)(((kc)&7)*2)*512)
    #define PSTORE(buf, v) { bf16x4 pk; pk[0]=(bf16_t)(v).x; pk[1]=(bf16_t)(v).y; \
        pk[2]=(bf16_t)(v).z; pk[3]=(bf16_t)(v).w; \
        *(bf16x4*)(lds + (buf)*4096 + wbyte) = pk; }
    // LDS-only fence + raw barrier: does NOT drain vmcnt (global prefetch survives)
    #define LBAR() { asm volatile("s_waitcnt lgkmcnt(0)" ::: "memory"); \
        __builtin_amdgcn_sched_barrier(0); \
        __builtin_amdgcn_s_barrier(); \
        __builtin_amdgcn_sched_barrier(0); }

    float4 va, vb;
    PLOAD(va, 0); PLOAD(vb, 1);
    PSTORE(0, va); PLOAD(va, 2);
    PSTORE(1, vb); PLOAD(vb, 3);
    LBAR();

    for (int kc = 0; kc < 24; kc++) {
        const int buf = kc & 1;
        bf16x8 af0 = *(const bf16x8*)(lds + buf*4096 + rbyte);
        bf16x8 af1 = *(const bf16x8*)(lds + buf*4096 + rbyte + 512);
        LBAR();                                // my reads done; writes of kc-1 visible
        if (kc < 22) {
            if (buf == 0) { PSTORE(0, va); if (kc < 20) PLOAD(va, kc+4); }
            else          { PSTORE(1, vb); if (kc < 20) PLOAD(vb, kc+4); }
        }
        #pragma unroll
        for (int fj = 0; fj < 7; fj++) {
            int n = wn*112 + fj*16 + l15;
            bf16x8 bv = *(const bf16x8*)(wcatT + (size_t)n*768 + kc*32 + l4*8);
            acc[0][fj] = MFMA16(af0, bv, acc[0][fj]);
            acc[1][fj] = MFMA16(af1, bv, acc[1][fj]);
        }
    }
    #undef PLOAD
    #undef PSTORE
    #undef LBAR

    #pragma unroll
    for (int fi = 0; fi < 2; fi++)
    #pragma unroll
    for (int fj = 0; fj < 7; fj++) {
        int nn = wn*112 + fj*16 + l15;
        #pragma unroll
        for (int rr = 0; rr < 4; rr++) {
            int pp = p0 + wp*32 + fi*16 + l4*4 + rr;
            float v = acc[fi][fj][rr];
            size_t rowb = (size_t)bt*1024 + pp;
            if (nn < 64)       keyb[rowb*64 + nn] = (bf16_t)v;
            else if (nn == 64) msb[rowb] = v*v + 1.f;
            else if (nn < 129) qeb[rowb*64 + (nn-65)] = (bf16_t)(1.f/(1.f+expf(-v)));
            else if (nn < 385) f16b[rowb*256 + (nn-129)] = (bf16_t)v;
        }
    }
}

// ---------------- Qfeat + fused feat0 partial reduce ----------------
// grid (32 bt, 128), block (64,8)
__global__ __launch_bounds__(512)
void k_qf(const bf16_t* __restrict__ keyb, const bf16_t* __restrict__ qeb,
          bf16_t* __restrict__ qfb, float* __restrict__ out)
{
    int bt = blockIdx.x;
    int p = blockIdx.y*8 + threadIdx.y;
    int c = threadIdx.x;
    size_t rowb = (size_t)bt*1024 + p;
    float qk = (float)keyb[rowb*64 + c];
    float qv = (float)qeb[rowb*64 + c];
    float bsq = qv*qk*qk;
    #pragma unroll
    for (int off = 32; off; off >>= 1) bsq += __shfl_xor(bsq, off);
    bf16_t* q = qfb + rowb*160;
    q[c]      = (bf16_t)(qv*qk);
    q[64 + c] = (bf16_t)qv;
    if (c == 0) q[128] = (bf16_t)bsq;
    if (c < 31) q[129 + c] = (bf16_t)0.f;
    if ((bt & 15) == 0) {                      // t==0: feat0 = mean over p of key
        __shared__ float fred[64];
        if (threadIdx.y == 0) fred[c] = 0.f;
        __syncthreads();
        atomicAdd(&fred[c], qk);
        __syncthreads();
        if (threadIdx.y == 0)
            atomicAdd(&out[(size_t)(bt >> 4)*1024 + c], fred[c]*(1.f/1024.f));
    }
}

// ---------------- t=0 mask: aggregate + 16x16 avg-pool (coalesced) ----------------
__global__ __launch_bounds__(256)
void k_mask0(const float* __restrict__ im, float* __restrict__ wmask)
{
    int blk = blockIdx.x;
    int b = blk >> 5, i = blk & 31;
    int tid = threadIdx.x;
    int xq = tid & 127, yh = tid >> 7;
    const float* base = im + (size_t)b*262144 + (size_t)(i*16)*512;
    float s = 0.f;
    for (int yy = 0; yy < 8; yy++) {
        int y = yy*2 + yh;
        float4 v = *(const float4*)(base + (size_t)y*512 + xq*4);
        float e[4] = {v.x, v.y, v.z, v.w};
        #pragma unroll
        for (int u = 0; u < 4; u++) {
            float pc = fminf(fmaxf(e[u],      1e-7f), 1.f-1e-7f);
            float qc = fminf(fmaxf(1.f-e[u],  1e-7f), 1.f-1e-7f);
            s += pc*pc/(pc*pc + qc*qc);
        }
    }
    __shared__ float red[32];
    if (tid < 32) red[tid] = 0.f;
    __syncthreads();
    atomicAdd(&red[xq >> 2], s);
    __syncthreads();
    if (tid < 32) wmask[b*1024 + i*32 + tid] = red[tid]*(1.f/256.f);
}

// ---------------- per-slot prep: kf rows + vhT GEMM ----------------
// grid (32, 2), block 128 (2 waves, 32 rows per block)
__global__ __launch_bounds__(128)
void k_prep(const bf16_t* __restrict__ f16b, const bf16_t* __restrict__ keyb,
            const float* __restrict__ msb, const float* __restrict__ wmk,
            const bf16_t* __restrict__ wvhT, const float* __restrict__ wvh1,
            bf16_t* __restrict__ kfb, bf16_t* __restrict__ vhT, int tm, int slot)
{
    int b = blockIdx.y, n0 = blockIdx.x*32;
    int tid = threadIdx.x, lane = tid & 63, w = tid >> 6;
    // ---- kf fill ----
    {
        int row = n0 + (tid >> 2), q = tid & 3;
        size_t rowb = (size_t)(b*16 + tm)*1024 + row;
        float m = msb[rowb];
        bf16_t* kr = kfb + ((size_t)b*3072 + slot*1024 + row)*160;
        bf16x8 k0v = *(const bf16x8*)(keyb + rowb*64 + q*16);
        bf16x8 k1v = *(const bf16x8*)(keyb + rowb*64 + q*16 + 8);
        bf16x8 o0, o1, s0, s1;
        #pragma unroll
        for (int u = 0; u < 8; u++) {
            float mk0 = (float)k0v[u], mk1 = (float)k1v[u];
            o0[u] = (bf16_t)( m*mk0*0.25f);       o1[u] = (bf16_t)( m*mk1*0.25f);
            s0[u] = (bf16_t)(-m*mk0*mk0*0.125f);  s1[u] = (bf16_t)(-m*mk1*mk1*0.125f);
        }
        *(bf16x8*)(kr + q*16)      = o0;  *(bf16x8*)(kr + q*16 + 8)      = o1;
        *(bf16x8*)(kr + 64 + q*16) = s0;  *(bf16x8*)(kr + 64 + q*16 + 8) = s1;
        if (q == 0) kr[128] = (bf16_t)(-m*0.125f);
        else if (q == 1) { for (int u = 0; u < 15; u++) kr[129+u] = (bf16_t)0.f; }
        else if (q == 2) { for (int u = 0; u < 16; u++) kr[144+u] = (bf16_t)0.f; }
    }
    // ---- vh GEMM: 32 n-rows x 80 c, K=256 ----
    int l15 = lane & 15, l4 = lane >> 4;
    const bf16_t* A = f16b + ((size_t)(b*16 + tm)*1024 + n0 + w*16 + l15)*256;
    f32x4 acc[5] = {};
    #pragma unroll
    for (int ks = 0; ks < 8; ks++) {
        bf16x8 a0 = *(const bf16x8*)(A + ks*32 + l4*8);
        #pragma unroll
        for (int cf = 0; cf < 5; cf++) {
            bf16x8 bv = *(const bf16x8*)(wvhT + (size_t)(cf*16 + l15)*256 + ks*32 + l4*8);
            acc[cf] = MFMA16(a0, bv, acc[cf]);
        }
    }
    #pragma unroll
    for (int cf = 0; cf < 5; cf++) {
        int cc = cf*16 + l15;
        float w1 = (cc < 65) ? wvh1[cc] : 0.f;
        #pragma unroll
        for (int rr = 0; rr < 4; rr++) {
            int p = n0 + w*16 + l4*4 + rr;
            float val;
            if (cc < 65)      val = acc[cf][rr] + wmk[b*1024 + p]*w1;
            else              val = (cc == 65) ? 1.f : 0.f;
            vhT[(size_t)b*393216 + (size_t)cc*3072 + slot*1024 + p] = (bf16_t)val;
        }
    }
}

// ---------------- value (MFMA): V = f16 @ Wv[0:256] + wmask*Wv[256] (slots 0,2) ----------------
__global__ __launch_bounds__(256)
void k_value(const bf16_t* __restrict__ f16b, const float* __restrict__ wmk,
             const bf16_t* __restrict__ WvT, const float* __restrict__ Wv,
             bf16_t* __restrict__ vb, int t, int slot)
{
    int b = blockIdx.z;
    int n0 = blockIdx.x*64, p0 = blockIdx.y*64;
    const int tid = threadIdx.x, lane = tid & 63, w = tid >> 6;
    const int wr = w >> 1, wc = w & 1, l15 = lane & 15, l4 = lane >> 4;
    const bf16_t* A = f16b + ((size_t)(b*16 + t)*1024 + p0)*256;
    f32x4 acc[2][2] = {};
    int ar = wr*32 + l15, bc = n0 + wc*32 + l15, koff = l4*8;
    #pragma unroll
    for (int ks = 0; ks < 8; ks++) {
        bf16x8 a0 = *(const bf16x8*)(A + (size_t)ar*256 + ks*32 + koff);
        bf16x8 a1 = *(const bf16x8*)(A + (size_t)(ar+16)*256 + ks*32 + koff);
        bf16x8 b0 = *(const bf16x8*)(WvT + (size_t)bc*256 + ks*32 + koff);
        bf16x8 b1 = *(const bf16x8*)(WvT + (size_t)(bc+16)*256 + ks*32 + koff);
        acc[0][0] = MFMA16(a0, b0, acc[0][0]);
        acc[0][1] = MFMA16(a0, b1, acc[0][1]);
        acc[1][0] = MFMA16(a1, b0, acc[1][0]);
        acc[1][1] = MFMA16(a1, b1, acc[1][1]);
    }
    #pragma unroll
    for (int fi = 0; fi < 2; fi++)
    #pragma unroll
    for (int fj = 0; fj < 2; fj++) {
        int nn = n0 + wc*32 + fj*16 + l15;
        float wvl = Wv[131072 + nn];
        #pragma unroll
        for (int rr = 0; rr < 4; rr++) {
            int pp = p0 + wr*32 + fi*16 + l4*4 + rr;
            float wm = wmk[b*1024 + pp];
            vb[((size_t)b*3072 + slot*1024 + pp)*512 + nn] = (bf16_t)(acc[fi][fj][rr] + wm*wvl);
        }
    }
}

// ---------------- pre16 (MFMA): f16 @ [Whd_lo|Wdec_lo] -> [p][65] ----------------
__global__ __launch_bounds__(256)
void k_pre16(const bf16_t* __restrict__ f16b, const bf16_t* __restrict__ whfT,
             bf16_t* __restrict__ p16b)
{
    int bt = blockIdx.y;
    int p0 = blockIdx.x*64;
    const int tid = threadIdx.x, lane = tid & 63, w = tid >> 6;
    const int wr = w >> 1, wc = w & 1, l15 = lane & 15, l4 = lane >> 4;
    const bf16_t* A = f16b + ((size_t)bt*1024 + p0)*256;
    f32x4 acc[2][4] = {};
    int ar = wr*32 + l15, koff = l4*8;
    #pragma unroll
    for (int ks = 0; ks < 8; ks++) {
        bf16x8 a0 = *(const bf16x8*)(A + (size_t)ar*256 + ks*32 + koff);
        bf16x8 a1 = *(const bf16x8*)(A + (size_t)(ar+16)*256 + ks*32 + koff);
        #pragma unroll
        for (int fj = 0; fj < 4; fj++) {
            int cc = wc*64 + fj*16 + l15;
            bf16x8 bv = *(const bf16x8*)(whfT + (size_t)cc*256 + ks*32 + koff);
            acc[0][fj] = MFMA16(a0, bv, acc[0][fj]);
            acc[1][fj] = MFMA16(a1, bv, acc[1][fj]);
        }
    }
    #pragma unroll
    for (int fi = 0; fi < 2; fi++)
    #pragma unroll
    for (int fj = 0; fj < 4; fj++) {
        int cc = wc*64 + fj*16 + l15;
        if (cc < 65) {
            #pragma unroll
            for (int rr = 0; rr < 4; rr++) {
                int pp = p0 + wr*32 + fi*16 + l4*4 + rr;
                p16b[((size_t)bt*1024 + pp)*72 + cc] = (bf16_t)acc[fi][fj][rr];
            }
        }
    }
}

// ---------------- split-N attention: exp(S)·Vh partials (sim<=0, no max/sum) ----------------
__global__ __launch_bounds__(256)
void k_att(const bf16_t* __restrict__ qfb, const bf16_t* __restrict__ kfb,
           const bf16_t* __restrict__ vhT, float* __restrict__ PVp, int t0)
{
    int b = blockIdx.z & 1, sl = blockIdx.z >> 1;
    int ts = blockIdx.y, t = t0 + ts, p0 = blockIdx.x*64;
    int n_base = sl*256;
    int tid = threadIdx.x, lane = tid & 63, w = tid >> 6;
    int l15 = lane & 15, l4 = lane >> 4;
    __shared__ __align__(16) bf16_t P_lds[4][16][72];

    const bf16_t* Q = qfb + ((size_t)(b*16 + t)*1024 + p0 + w*16 + l15)*160 + l4*8;
    bf16x8 aq[5];
    #pragma unroll
    for (int kc = 0; kc < 5; kc++) aq[kc] = *(const bf16x8*)(Q + kc*32);

    const bf16_t* K  = kfb + ((size_t)b*3072 + n_base)*160;
    const bf16_t* Vh = vhT + (size_t)b*393216 + n_base;
    f32x4 o[5] = {};

    for (int n0 = 0; n0 < 256; n0 += 64) {
        f32x4 s[4] = {};
        #pragma unroll
        for (int kc = 0; kc < 5; kc++) {
            #pragma unroll
            for (int nf = 0; nf < 4; nf++) {
                bf16x8 bk = *(const bf16x8*)(K + (size_t)(n0 + nf*16 + l15)*160 + kc*32 + l4*8);
                s[nf] = MFMA16(aq[kc], bk, s[nf]);
            }
        }
        #pragma unroll
        for (int nf = 0; nf < 4; nf++) {
            #pragma unroll
            for (int rr = 0; rr < 4; rr++) {
                float pe = __expf(s[nf][rr]);
                P_lds[w][l4*4 + rr][nf*16 + l15] = (bf16_t)pe;
            }
        }
        #pragma unroll
        for (int kc2 = 0; kc2 < 2; kc2++) {
            bf16x8 ap = *(const bf16x8*)&P_lds[w][l15][kc2*32 + l4*8];
            #pragma unroll
            for (int cf = 0; cf < 5; cf++) {
                bf16x8 bv = *(const bf16x8*)(Vh + (size_t)(cf*16 + l15)*3072 + n0 + kc2*32 + l4*8);
                o[cf] = MFMA16(ap, bv, o[cf]);
            }
        }
    }
    float* O = PVp + (size_t)sl*PVSTR + ((size_t)((b*5 + ts)*1024) + p0 + w*16)*72;
    #pragma unroll
    for (int cf = 0; cf < 5; cf++) {
        int cc = cf*16 + l15;
        if (cc < 66) {
            #pragma unroll
            for (int rr = 0; rr < 4; rr++)
                O[(size_t)(l4*4 + rr)*72 + cc] = o[cf][rr];
        }
    }
}

// ---------------- sequential 5-step chain; sums PV slices, divides by col65 ----------------
__global__ __launch_bounds__(256)
void k_chain2(const bf16_t* __restrict__ p16b, const float* __restrict__ PVp,
              const float* __restrict__ whhbuf, float* __restrict__ hidden,
              float* __restrict__ wmk, float* __restrict__ mh, int t0, int ph, int ns)
{
    int b = blockIdx.y;
    int tid = threadIdx.x, lane = tid & 63, w = tid >> 6;
    int p = blockIdx.x*4 + w;
    __shared__ float whh_s[64][66];
    __shared__ float hid_s[4][64];
    for (int idx = tid; idx < 64*66; idx += 256) whh_s[idx/66][idx%66] = whhbuf[idx];
    float h = hidden[((size_t)b*1024 + p)*64 + lane];
    hid_s[w][lane] = h;
    __syncthreads();
    float wd = whh_s[lane][64];
    for (int ts = 0; ts < 5; ts++) {
        int t = t0 + ts;
        size_t r16 = ((size_t)(b*16 + t)*1024 + p)*72;
        size_t rpv = ((size_t)((b*5 + ts)*1024) + p)*72;
        float pvc = 0.f, pv64 = 0.f, pv65 = 0.f;
        for (int s2 = 0; s2 < ns; s2++) {
            const float* bp = PVp + (size_t)s2*PVSTR + rpv;
            pvc  += bp[lane];
            pv64 += bp[64];
            pv65 += bp[65];
        }
        float rinv  = 1.f/pv65;
        float pre   = (float)p16b[r16 + lane] + pvc*rinv;
        float fgpre = (float)p16b[r16 + 64]   + pv64*rinv;
        float s = pre;
        #pragma unroll 8
        for (int k = 0; k < 64; k++) s += hid_s[w][k]*whh_s[k][lane];
        float hl = tanhf(s);
        float fgs = hl*wd;
        #pragma unroll
        for (int off = 1; off < 64; off <<= 1) fgs += __shfl_xor(fgs, off);
        float fg = fgpre + fgs;
        float m = 1.f/(1.f+expf(-fg));
        size_t rmh = ((size_t)(b*15 + ph*5 + ts)*1024 + p)*66;
        mh[rmh + lane] = m*hl;
        if (lane == 0) mh[rmh + 64] = m;
        if (ts == 4 && lane == 0) wmk[b*1024 + p] = m;
        h = hl;
        __syncthreads();
        hid_s[w][lane] = h;
        __syncthreads();
    }
    hidden[((size_t)b*1024 + p)*64 + lane] = h;
}

// ---------------- hidden update (MFMA): tanh([V | hid?] @ Wh2) ----------------
__global__ __launch_bounds__(256)
void k_hidm(const bf16_t* __restrict__ vb, const bf16_t* __restrict__ wh2T,
            float* __restrict__ hidden, int vslot, int has_h)
{
    int b = blockIdx.y, p0 = blockIdx.x*64;
    int tid = threadIdx.x, lane = tid & 63, w = tid >> 6;
    int l15 = lane & 15, l4 = lane >> 4;
    int arow = p0 + w*16 + l15;
    const bf16_t* A = vb + ((size_t)b*3072 + vslot*1024 + arow)*512;
    const float* Hp = hidden + ((size_t)b*1024 + arow)*64;
    f32x4 acc[4] = {};
    int kiters = has_h ? 18 : 16;
    for (int ks = 0; ks < kiters; ks++) {
        bf16x8 a0;
        if (ks < 16) a0 = *(const bf16x8*)(A + ks*32 + l4*8);
        else {
            int ko = (ks-16)*32 + l4*8;
            float4 h0 = *(const float4*)(Hp + ko);
            float4 h1 = *(const float4*)(Hp + ko + 4);
            a0[0]=(bf16_t)h0.x; a0[1]=(bf16_t)h0.y; a0[2]=(bf16_t)h0.z; a0[3]=(bf16_t)h0.w;
            a0[4]=(bf16_t)h1.x; a0[5]=(bf16_t)h1.y; a0[6]=(bf16_t)h1.z; a0[7]=(bf16_t)h1.w;
        }
        #pragma unroll
        for (int cf = 0; cf < 4; cf++) {
            bf16x8 bv = *(const bf16x8*)(wh2T + (size_t)(cf*16 + l15)*576 + ks*32 + l4*8);
            acc[cf] = MFMA16(a0, bv, acc[cf]);
        }
    }
    #pragma unroll
    for (int cf = 0; cf < 4; cf++) {
        int cc = cf*16 + l15;
        #pragma unroll
        for (int rr = 0; rr < 4; rr++) {
            int p = p0 + w*16 + l4*4 + rr;
            hidden[((size_t)b*1024 + p)*64 + cc] = tanhf(acc[cf][rr]);
        }
    }
}

// ---------------- feats t=1..15: weighted mean reduce ----------------
__global__ __launch_bounds__(256)
void k_feats(const float* __restrict__ mh, float* __restrict__ out)
{
    int slot = blockIdx.x, b = blockIdx.y, t = slot + 1;
    int tid = threadIdx.x, c = tid & 63, g = tid >> 6;
    const float* base = mh + (size_t)(b*15 + slot)*1024*66;
    float s = 0.f, sm = 0.f;
    for (int p = g; p < 1024; p += 4) {
        s += base[(size_t)p*66 + c];
        if (c == 0) sm += base[(size_t)p*66 + 64];
    }
    __shared__ float red[4][64];
    __shared__ float redm[4];
    red[g][c] = s;
    if (c == 0) redm[g] = sm;
    __syncthreads();
    if (g == 0) {
        float tot  = red[0][c] + red[1][c] + red[2][c] + red[3][c];
        float totm = redm[0] + redm[1] + redm[2] + redm[3];
        out[(size_t)(b*16 + t)*64 + c] = tot / fmaxf(totm, 1e-6f);
    }
}

// ---------------- host launcher ----------------
extern "C" void kernel_launch(void* const* d_in, const int* in_sizes, int n_in,
                              void* d_out, int out_size, void* d_ws, size_t ws_size,
                              hipStream_t stream)
{
    (void)in_sizes; (void)n_in; (void)out_size;
    if (ws_size < ws_need*sizeof(float)) return;
    const float* frames = (const float*)d_in[0];
    const float* imask  = (const float*)d_in[1];
    const float* Wk   = (const float*)d_in[3];
    const float* Wsh  = (const float*)d_in[4];
    const float* Wse  = (const float*)d_in[5];
    const float* Wf   = (const float*)d_in[6];
    const float* Wv   = (const float*)d_in[7];
    const float* Wh2  = (const float*)d_in[8];
    const float* Whd  = (const float*)d_in[9];
    const float* Wdec = (const float*)d_in[10];
    float* out = (float*)d_out;
    float* ws  = (float*)d_ws;

    bf16_t* wcatT = (bf16_t*)(ws + o_wcatT);
    bf16_t* whfT  = (bf16_t*)(ws + o_whfT);
    bf16_t* wvhT  = (bf16_t*)(ws + o_wvhT);
    float*  wvh1  = ws + o_wvh1;
    bf16_t* WvT   = (bf16_t*)(ws + o_WvT);
    float*  whh   = ws + o_whh;
    bf16_t* wh2T  = (bf16_t*)(ws + o_wh2T);
    bf16_t* keyb  = (bf16_t*)(ws + o_keyb);
    float*  msb   = ws + o_ms;
    bf16_t* qeb   = (bf16_t*)(ws + o_qeb);
    bf16_t* f16b  = (bf16_t*)(ws + o_f16b);
    bf16_t* qfb   = (bf16_t*)(ws + o_qfb);
    bf16_t* kfb   = (bf16_t*)(ws + o_kfb);
    bf16_t* vb    = (bf16_t*)(ws + o_vb);
    bf16_t* vhT   = (bf16_t*)(ws + o_vhT);
    float*  PVp   = ws + o_pv;
    bf16_t* p16b  = (bf16_t*)(ws + o_p16);
    float*  mh    = ws + o_mh;
    float*  hid   = ws + o_hid;
    float*  wmk   = ws + o_wmk;

    k_init<<<2226, 256, 0, stream>>>(Wk, Wsh, Wse, Wf, Wv, Wh2, Whd, Wdec,
                                     wcatT, whfT, WvT, whh, wh2T, out, wvhT, wvh1);
    k_proj<<<dim3(16,32), 512, 0, stream>>>(frames, wcatT, keyb, msb, qeb, f16b);
    k_qf<<<dim3(32,128), dim3(64,8), 0, stream>>>(keyb, qeb, qfb, out);
    k_mask0<<<64, 256, 0, stream>>>(imask, wmk);
    k_prep<<<dim3(32,2), 128, 0, stream>>>(f16b, keyb, msb, wmk, wvhT, wvh1, kfb, vhT, 0, 0);
    k_value<<<dim3(8,16,2), 256, 0, stream>>>(f16b, wmk, WvT, Wv, vb, 0, 0);
    k_hidm<<<dim3(16,2), 256, 0, stream>>>(vb, wh2T, hid, 0, 0);
    k_pre16<<<dim3(16,32), 256, 0, stream>>>(f16b, whfT, p16b);

    for (int ph = 0; ph < 3; ph++) {
        int t0 = 1 + ph*5;
        int ns = (ph + 1)*4;            // N/256 slices: 4, 8, 12
        k_att<<<dim3(16,5,2*ns), 256, 0, stream>>>(qfb, kfb, vhT, PVp, t0);
        k_chain2<<<dim3(256,2), 256, 0, stream>>>(p16b, PVp, whh, hid, wmk, mh, t0, ph, ns);
        if (ph < 2) {
            int tm = t0 + 4, slot = ph + 1;
            k_prep<<<dim3(32,2), 128, 0, stream>>>(f16b, keyb, msb, wmk, wvhT, wvh1, kfb, vhT, tm, slot);
            if (ph == 1) {
                k_value<<<dim3(8,16,2), 256, 0, stream>>>(f16b, wmk, WvT, Wv, vb, tm, slot);
                k_hidm<<<dim3(16,2), 256, 0, stream>>>(vb, wh2T, hid, 2, 1);
            }
        }
    }
    k_feats<<<dim3(15,2), 256, 0, stream>>>(mh, out);
}

// Round 14
// 431.917 us; speedup vs baseline: 1.2924x; 1.2389x over previous
//
#include <hip/hip_runtime.h>
#include <cstdint>

typedef __bf16 bf16_t;
typedef __attribute__((ext_vector_type(8))) __bf16 bf16x8;
typedef __attribute__((ext_vector_type(4))) __bf16 bf16x4;
typedef __attribute__((ext_vector_type(4))) float f32x4;

#define MFMA16(a,b,c) __builtin_amdgcn_mfma_f32_16x16x32_bf16((a),(b),(c),0,0,0)

// ---------------- workspace offsets (float units) ----------------
constexpr size_t PVSTR   = (size_t)2*5*1024*72;  // one N-slice of PV partials
constexpr size_t o_wcatT = 0;                    // bf16 [448][768]
constexpr size_t o_whfT  = o_wcatT + 172032;     // bf16 [128][256]
constexpr size_t o_wvhT  = o_whfT  + 16384;      // bf16 [80][256]  fused Wv@Whv (transposed)
constexpr size_t o_wvh1  = o_wvhT  + 10240;      // f32  [65]  (mask-row of fused weight)
constexpr size_t o_WvT   = o_wvh1  + 80;         // bf16 [512][256]
constexpr size_t o_whh   = o_WvT   + 65536;      // f32  [64][66]
constexpr size_t o_wh2T  = o_whh   + 4224;       // bf16 [64][576]
constexpr size_t o_keyb  = o_wh2T  + 18432;      // bf16 [B*T*1024][64]
constexpr size_t o_ms    = o_keyb  + 1048576;    // f32  [B*T*1024]
constexpr size_t o_qeb   = o_ms    + 32768;      // bf16 [B*T*1024][64]
constexpr size_t o_f16b  = o_qeb   + 1048576;    // bf16 [B*T*1024][256]
constexpr size_t o_qfb   = o_f16b  + 4194304;    // bf16 [B*T*1024][160]
constexpr size_t o_kfb   = o_qfb   + 2621440;    // bf16 [B*3072][160]
constexpr size_t o_vb    = o_kfb   + 491520;     // bf16 [B*3072][512] (slots 0,2 used)
constexpr size_t o_vhT   = o_vb    + 1572864;    // bf16 [B][128][3072] (row65 = ones)
constexpr size_t o_pv    = o_vhT   + 393216;     // f32  [12 slices][B][5][1024][72]
constexpr size_t o_p16   = o_pv    + 12*PVSTR;   // bf16 [B*T*1024][72]
constexpr size_t o_mh    = o_p16   + 1179648;    // f32  [B][15][1024][66]
constexpr size_t o_hid   = o_mh    + 2027520;    // f32  [B][1024][64]
constexpr size_t o_wmk   = o_hid   + 131072;     // f32  [B][1024]
constexpr size_t ws_need = o_wmk   + 2048;

// ---------------- init: weight panels + fused Wv@Whv + zero out[t=0] ----------------
__global__ __launch_bounds__(256)
void k_init(const float* __restrict__ Wk, const float* __restrict__ Wsh,
            const float* __restrict__ Wse, const float* __restrict__ Wf,
            const float* __restrict__ Wv, const float* __restrict__ Wh2,
            const float* __restrict__ Whd, const float* __restrict__ Wdec,
            bf16_t* __restrict__ wcatT, bf16_t* __restrict__ whfT,
            bf16_t* __restrict__ WvT, float* __restrict__ whh,
            bf16_t* __restrict__ wh2T, float* __restrict__ out,
            bf16_t* __restrict__ wvhT, float* __restrict__ wvh1)
{
    int idx = blockIdx.x*256 + threadIdx.x;
    if (idx < 344064) {                       // wcatT[n][k] n<448 k<768
        int n = idx/768, k = idx%768;
        float v = 0.f;
        if (n < 64)       v = Wk[k*64+n];
        else if (n == 64) v = Wsh[k];
        else if (n < 129) v = Wse[k*64+(n-65)];
        else if (n < 385) v = Wf[k*256+(n-129)];
        wcatT[idx] = (bf16_t)v;
        return;
    }
    idx -= 344064;
    if (idx < 32768) {                        // whfT[c][k] c<128 k<256
        int c = idx/256, k = idx%256;
        float v = 0.f;
        if (c < 64) v = Whd[k*64+c]; else if (c == 64) v = Wdec[k];
        whfT[idx] = (bf16_t)v;
        return;
    }
    idx -= 32768;
    if (idx < 131072) {                       // WvT[n][k] n<512 k<256
        int n = idx/256, k = idx%256;
        WvT[idx] = (bf16_t)Wv[k*512+n];
        return;
    }
    idx -= 131072;
    if (idx < 4224) {                         // whh[k][c] (stride 66), c<65 real
        int k = idx/66, c = idx%66;
        float v = 0.f;
        if (c < 64) v = Whd[(768+k)*64+c]; else if (c == 64) v = Wdec[768+k];
        whh[idx] = v;
        return;
    }
    idx -= 4224;
    if (idx < 36864) {                        // wh2T[c][k] c<64 k<576
        int c = idx/576, k = idx%576;
        wh2T[idx] = (bf16_t)Wh2[k*64+c];
        return;
    }
    idx -= 36864;
    if (idx < 128) {                          // zero out[t=0] (feat0 atomics)
        int b = idx>>6, c = idx&63;
        out[(size_t)b*1024 + c] = 0.f;
        return;
    }
    idx -= 128;
    if (idx < 20480) {                        // wvhT[c][k] = (Wv@whv)[k][c]
        int k = idx / 80, c = idx % 80;
        float s = 0.f;
        if (c < 65) {
            for (int j = 0; j < 512; j++) {
                float hv = (c < 64) ? Whd[(256+j)*64 + c] : Wdec[256 + j];
                s = fmaf(Wv[k*512 + j], hv, s);
            }
        }
        wvhT[(size_t)c*256 + k] = (bf16_t)s;
        return;
    }
    idx -= 20480;
    if (idx < 65) {                           // mask-row of fused weight
        int c = idx;
        float s = 0.f;
        for (int j = 0; j < 512; j++) {
            float hv = (c < 64) ? Whd[(256+j)*64 + c] : Wdec[256 + j];
            s = fmaf(Wv[256*512 + j], hv, s);
        }
        wvh1[c] = s;
    }
}

// ---------------- projection GEMM v6: 2 frames per block share the B panel ---------
// grid (16 px, 16 bt-pair), block 512 (8 waves). Each B fragment feeds 4 MFMAs
// (2 frames x 2 row-halves) -> per-frame L1 request count ~1.8x lower than v5.
__global__ __launch_bounds__(512)
void k_proj(const float* __restrict__ frames, const bf16_t* __restrict__ wcatT,
            bf16_t* __restrict__ keyb, float* __restrict__ msb,
            bf16_t* __restrict__ qeb, bf16_t* __restrict__ f16b)
{
    const int bx = blockIdx.x, btp = blockIdx.y;
    const int p0 = bx*64;
    const int tid = threadIdx.x, lane = tid & 63, w = tid >> 6;
    const int wp = w >> 2, wn = w & 3;
    const int l15 = lane & 15, l4 = lane >> 4;
    __shared__ __align__(16) bf16_t Al[2][2][4][512];  // [frame][buf][imgrow][512] = 16KB
    f32x4 acc[2][2][7] = {};                           // [frame][fi][fj]
    const float* fb0 = frames + (size_t)(btp*2)*786432;
    const float* fb1 = fb0 + 786432;

    const int lr = tid >> 7, lxb = (tid & 127)*8;
    const size_t grow = (size_t)((bx*2 + (lr>>1))*16 + (lr&1))*512 + (tid & 127)*4;
    const float* gbase0 = fb0 + grow;
    const float* gbase1 = fb1 + grow;
    const int wbyte = lr*1024 + (lxb ^ (((lxb>>7)&3)<<4));
    const int rb_in = l15*32 + (l4&1)*16;
    const int rbyte = (wp*2 + (l4>>1))*1024 + (rb_in ^ (((rb_in>>7)&3)<<4));
    char* lds = (char*)&Al[0][0][0][0];

    #define PLOAD(dst, gb, kc) dst = *(const float4*)((gb) + (size_t)((kc)>>3)*262144 + (size_t)(((kc)&7)*2)*512)
    #define PSTORE(f, buf, v) { bf16x4 pk; pk[0]=(bf16_t)(v).x; pk[1]=(bf16_t)(v).y; \
        pk[2]=(bf16_t)(v).z; pk[3]=(bf16_t)(v).w; \
        *(bf16x4*)(lds + (f)*8192 + (buf)*4096 + wbyte) = pk; }
    #define LBAR() { asm volatile("s_waitcnt lgkmcnt(0)" ::: "memory"); \
        __builtin_amdgcn_sched_barrier(0); \
        __builtin_amdgcn_s_barrier(); \
        __builtin_amdgcn_sched_barrier(0); }

    float4 va0, vb0, va1, vb1;
    PLOAD(va0, gbase0, 0); PLOAD(va1, gbase1, 0);
    PLOAD(vb0, gbase0, 1); PLOAD(vb1, gbase1, 1);
    PSTORE(0, 0, va0); PSTORE(1, 0, va1);
    PLOAD(va0, gbase0, 2); PLOAD(va1, gbase1, 2);
    PSTORE(0, 1, vb0); PSTORE(1, 1, vb1);
    PLOAD(vb0, gbase0, 3); PLOAD(vb1, gbase1, 3);
    LBAR();

    for (int kc = 0; kc < 24; kc++) {
        const int buf = kc & 1;
        bf16x8 a00 = *(const bf16x8*)(lds + buf*4096 + rbyte);
        bf16x8 a01 = *(const bf16x8*)(lds + buf*4096 + rbyte + 512);
        bf16x8 a10 = *(const bf16x8*)(lds + 8192 + buf*4096 + rbyte);
        bf16x8 a11 = *(const bf16x8*)(lds + 8192 + buf*4096 + rbyte + 512);
        LBAR();                                // my reads done; stores of kc-1 visible
        if (kc < 22) {
            if (buf == 0) {
                PSTORE(0, 0, va0); PSTORE(1, 0, va1);
                if (kc < 20) { PLOAD(va0, gbase0, kc+4); PLOAD(va1, gbase1, kc+4); }
            } else {
                PSTORE(0, 1, vb0); PSTORE(1, 1, vb1);
                if (kc < 20) { PLOAD(vb0, gbase0, kc+4); PLOAD(vb1, gbase1, kc+4); }
            }
        }
        #pragma unroll
        for (int fj = 0; fj < 7; fj++) {
            int n = wn*112 + fj*16 + l15;
            bf16x8 bv = *(const bf16x8*)(wcatT + (size_t)n*768 + kc*32 + l4*8);
            acc[0][0][fj] = MFMA16(a00, bv, acc[0][0][fj]);
            acc[0][1][fj] = MFMA16(a01, bv, acc[0][1][fj]);
            acc[1][0][fj] = MFMA16(a10, bv, acc[1][0][fj]);
            acc[1][1][fj] = MFMA16(a11, bv, acc[1][1][fj]);
        }
    }
    #undef PLOAD
    #undef PSTORE
    #undef LBAR

    #pragma unroll
    for (int f = 0; f < 2; f++) {
        int bt = btp*2 + f;
        #pragma unroll
        for (int fi = 0; fi < 2; fi++)
        #pragma unroll
        for (int fj = 0; fj < 7; fj++) {
            int nn = wn*112 + fj*16 + l15;
            #pragma unroll
            for (int rr = 0; rr < 4; rr++) {
                int pp = p0 + wp*32 + fi*16 + l4*4 + rr;
                float v = acc[f][fi][fj][rr];
                size_t rowb = (size_t)bt*1024 + pp;
                if (nn < 64)       keyb[rowb*64 + nn] = (bf16_t)v;
                else if (nn == 64) msb[rowb] = v*v + 1.f;
                else if (nn < 129) qeb[rowb*64 + (nn-65)] = (bf16_t)(1.f/(1.f+expf(-v)));
                else if (nn < 385) f16b[rowb*256 + (nn-129)] = (bf16_t)v;
            }
        }
    }
}

// ---------------- Qfeat + fused feat0 partial reduce ----------------
// grid (32 bt, 128), block (64,8)
__global__ __launch_bounds__(512)
void k_qf(const bf16_t* __restrict__ keyb, const bf16_t* __restrict__ qeb,
          bf16_t* __restrict__ qfb, float* __restrict__ out)
{
    int bt = blockIdx.x;
    int p = blockIdx.y*8 + threadIdx.y;
    int c = threadIdx.x;
    size_t rowb = (size_t)bt*1024 + p;
    float qk = (float)keyb[rowb*64 + c];
    float qv = (float)qeb[rowb*64 + c];
    float bsq = qv*qk*qk;
    #pragma unroll
    for (int off = 32; off; off >>= 1) bsq += __shfl_xor(bsq, off);
    bf16_t* q = qfb + rowb*160;
    q[c]      = (bf16_t)(qv*qk);
    q[64 + c] = (bf16_t)qv;
    if (c == 0) q[128] = (bf16_t)bsq;
    if (c < 31) q[129 + c] = (bf16_t)0.f;
    if ((bt & 15) == 0) {                      // t==0: feat0 = mean over p of key
        __shared__ float fred[64];
        if (threadIdx.y == 0) fred[c] = 0.f;
        __syncthreads();
        atomicAdd(&fred[c], qk);
        __syncthreads();
        if (threadIdx.y == 0)
            atomicAdd(&out[(size_t)(bt >> 4)*1024 + c], fred[c]*(1.f/1024.f));
    }
}

// ---------------- t=0 mask: aggregate + 16x16 avg-pool (coalesced) ----------------
__global__ __launch_bounds__(256)
void k_mask0(const float* __restrict__ im, float* __restrict__ wmask)
{
    int blk = blockIdx.x;
    int b = blk >> 5, i = blk & 31;
    int tid = threadIdx.x;
    int xq = tid & 127, yh = tid >> 7;
    const float* base = im + (size_t)b*262144 + (size_t)(i*16)*512;
    float s = 0.f;
    for (int yy = 0; yy < 8; yy++) {
        int y = yy*2 + yh;
        float4 v = *(const float4*)(base + (size_t)y*512 + xq*4);
        float e[4] = {v.x, v.y, v.z, v.w};
        #pragma unroll
        for (int u = 0; u < 4; u++) {
            float pc = fminf(fmaxf(e[u],      1e-7f), 1.f-1e-7f);
            float qc = fminf(fmaxf(1.f-e[u],  1e-7f), 1.f-1e-7f);
            s += pc*pc/(pc*pc + qc*qc);
        }
    }
    __shared__ float red[32];
    if (tid < 32) red[tid] = 0.f;
    __syncthreads();
    atomicAdd(&red[xq >> 2], s);
    __syncthreads();
    if (tid < 32) wmask[b*1024 + i*32 + tid] = red[tid]*(1.f/256.f);
}

// ---------------- per-slot prep: kf rows + vhT GEMM ----------------
// grid (32, 2), block 128 (2 waves, 32 rows per block)
__global__ __launch_bounds__(128)
void k_prep(const bf16_t* __restrict__ f16b, const bf16_t* __restrict__ keyb,
            const float* __restrict__ msb, const float* __restrict__ wmk,
            const bf16_t* __restrict__ wvhT, const float* __restrict__ wvh1,
            bf16_t* __restrict__ kfb, bf16_t* __restrict__ vhT, int tm, int slot)
{
    int b = blockIdx.y, n0 = blockIdx.x*32;
    int tid = threadIdx.x, lane = tid & 63, w = tid >> 6;
    // ---- kf fill ----
    {
        int row = n0 + (tid >> 2), q = tid & 3;
        size_t rowb = (size_t)(b*16 + tm)*1024 + row;
        float m = msb[rowb];
        bf16_t* kr = kfb + ((size_t)b*3072 + slot*1024 + row)*160;
        bf16x8 k0v = *(const bf16x8*)(keyb + rowb*64 + q*16);
        bf16x8 k1v = *(const bf16x8*)(keyb + rowb*64 + q*16 + 8);
        bf16x8 o0, o1, s0, s1;
        #pragma unroll
        for (int u = 0; u < 8; u++) {
            float mk0 = (float)k0v[u], mk1 = (float)k1v[u];
            o0[u] = (bf16_t)( m*mk0*0.25f);       o1[u] = (bf16_t)( m*mk1*0.25f);
            s0[u] = (bf16_t)(-m*mk0*mk0*0.125f);  s1[u] = (bf16_t)(-m*mk1*mk1*0.125f);
        }
        *(bf16x8*)(kr + q*16)      = o0;  *(bf16x8*)(kr + q*16 + 8)      = o1;
        *(bf16x8*)(kr + 64 + q*16) = s0;  *(bf16x8*)(kr + 64 + q*16 + 8) = s1;
        if (q == 0) kr[128] = (bf16_t)(-m*0.125f);
        else if (q == 1) { for (int u = 0; u < 15; u++) kr[129+u] = (bf16_t)0.f; }
        else if (q == 2) { for (int u = 0; u < 16; u++) kr[144+u] = (bf16_t)0.f; }
    }
    // ---- vh GEMM: 32 n-rows x 80 c, K=256 ----
    int l15 = lane & 15, l4 = lane >> 4;
    const bf16_t* A = f16b + ((size_t)(b*16 + tm)*1024 + n0 + w*16 + l15)*256;
    f32x4 acc[5] = {};
    #pragma unroll
    for (int ks = 0; ks < 8; ks++) {
        bf16x8 a0 = *(const bf16x8*)(A + ks*32 + l4*8);
        #pragma unroll
        for (int cf = 0; cf < 5; cf++) {
            bf16x8 bv = *(const bf16x8*)(wvhT + (size_t)(cf*16 + l15)*256 + ks*32 + l4*8);
            acc[cf] = MFMA16(a0, bv, acc[cf]);
        }
    }
    #pragma unroll
    for (int cf = 0; cf < 5; cf++) {
        int cc = cf*16 + l15;
        float w1 = (cc < 65) ? wvh1[cc] : 0.f;
        #pragma unroll
        for (int rr = 0; rr < 4; rr++) {
            int p = n0 + w*16 + l4*4 + rr;
            float val;
            if (cc < 65)      val = acc[cf][rr] + wmk[b*1024 + p]*w1;
            else              val = (cc == 65) ? 1.f : 0.f;
            vhT[(size_t)b*393216 + (size_t)cc*3072 + slot*1024 + p] = (bf16_t)val;
        }
    }
}

// ---------------- value (MFMA): V = f16 @ Wv[0:256] + wmask*Wv[256] (slots 0,2) ----------------
__global__ __launch_bounds__(256)
void k_value(const bf16_t* __restrict__ f16b, const float* __restrict__ wmk,
             const bf16_t* __restrict__ WvT, const float* __restrict__ Wv,
             bf16_t* __restrict__ vb, int t, int slot)
{
    int b = blockIdx.z;
    int n0 = blockIdx.x*64, p0 = blockIdx.y*64;
    const int tid = threadIdx.x, lane = tid & 63, w = tid >> 6;
    const int wr = w >> 1, wc = w & 1, l15 = lane & 15, l4 = lane >> 4;
    const bf16_t* A = f16b + ((size_t)(b*16 + t)*1024 + p0)*256;
    f32x4 acc[2][2] = {};
    int ar = wr*32 + l15, bc = n0 + wc*32 + l15, koff = l4*8;
    #pragma unroll
    for (int ks = 0; ks < 8; ks++) {
        bf16x8 a0 = *(const bf16x8*)(A + (size_t)ar*256 + ks*32 + koff);
        bf16x8 a1 = *(const bf16x8*)(A + (size_t)(ar+16)*256 + ks*32 + koff);
        bf16x8 b0 = *(const bf16x8*)(WvT + (size_t)bc*256 + ks*32 + koff);
        bf16x8 b1 = *(const bf16x8*)(WvT + (size_t)(bc+16)*256 + ks*32 + koff);
        acc[0][0] = MFMA16(a0, b0, acc[0][0]);
        acc[0][1] = MFMA16(a0, b1, acc[0][1]);
        acc[1][0] = MFMA16(a1, b0, acc[1][0]);
        acc[1][1] = MFMA16(a1, b1, acc[1][1]);
    }
    #pragma unroll
    for (int fi = 0; fi < 2; fi++)
    #pragma unroll
    for (int fj = 0; fj < 2; fj++) {
        int nn = n0 + wc*32 + fj*16 + l15;
        float wvl = Wv[131072 + nn];
        #pragma unroll
        for (int rr = 0; rr < 4; rr++) {
            int pp = p0 + wr*32 + fi*16 + l4*4 + rr;
            float wm = wmk[b*1024 + pp];
            vb[((size_t)b*3072 + slot*1024 + pp)*512 + nn] = (bf16_t)(acc[fi][fj][rr] + wm*wvl);
        }
    }
}

// ---------------- pre16 (MFMA): f16 @ [Whd_lo|Wdec_lo] -> [p][65] ----------------
__global__ __launch_bounds__(256)
void k_pre16(const bf16_t* __restrict__ f16b, const bf16_t* __restrict__ whfT,
             bf16_t* __restrict__ p16b)
{
    int bt = blockIdx.y;
    int p0 = blockIdx.x*64;
    const int tid = threadIdx.x, lane = tid & 63, w = tid >> 6;
    const int wr = w >> 1, wc = w & 1, l15 = lane & 15, l4 = lane >> 4;
    const bf16_t* A = f16b + ((size_t)bt*1024 + p0)*256;
    f32x4 acc[2][4] = {};
    int ar = wr*32 + l15, koff = l4*8;
    #pragma unroll
    for (int ks = 0; ks < 8; ks++) {
        bf16x8 a0 = *(const bf16x8*)(A + (size_t)ar*256 + ks*32 + koff);
        bf16x8 a1 = *(const bf16x8*)(A + (size_t)(ar+16)*256 + ks*32 + koff);
        #pragma unroll
        for (int fj = 0; fj < 4; fj++) {
            int cc = wc*64 + fj*16 + l15;
            bf16x8 bv = *(const bf16x8*)(whfT + (size_t)cc*256 + ks*32 + koff);
            acc[0][fj] = MFMA16(a0, bv, acc[0][fj]);
            acc[1][fj] = MFMA16(a1, bv, acc[1][fj]);
        }
    }
    #pragma unroll
    for (int fi = 0; fi < 2; fi++)
    #pragma unroll
    for (int fj = 0; fj < 4; fj++) {
        int cc = wc*64 + fj*16 + l15;
        if (cc < 65) {
            #pragma unroll
            for (int rr = 0; rr < 4; rr++) {
                int pp = p0 + wr*32 + fi*16 + l4*4 + rr;
                p16b[((size_t)bt*1024 + pp)*72 + cc] = (bf16_t)acc[fi][fj][rr];
            }
        }
    }
}

// ---------------- split-N attention v2: LDS-staged K/Vh shared by all 4 waves ------
// K chunk [64][160] staged at padded stride 168 (2-way bank alias = free);
// Vh chunk [80][64] at padded stride 72. One coalesced stage per n0-iter replaces
// 4 waves' duplicated 16-line frag loads (4x TA request cut). Math unchanged.
// grid (16 p0, 5 ts, 2b*ns), block 256 (4 waves).
__global__ __launch_bounds__(256)
void k_att(const bf16_t* __restrict__ qfb, const bf16_t* __restrict__ kfb,
           const bf16_t* __restrict__ vhT, float* __restrict__ PVp, int t0)
{
    int b = blockIdx.z & 1, sl = blockIdx.z >> 1;
    int ts = blockIdx.y, t = t0 + ts, p0 = blockIdx.x*64;
    int n_base = sl*256;
    int tid = threadIdx.x, lane = tid & 63, w = tid >> 6;
    int l15 = lane & 15, l4 = lane >> 4;
    __shared__ __align__(16) bf16_t K_lds[64][168];    // 21KB
    __shared__ __align__(16) bf16_t V_lds[80][72];     // 11.25KB
    __shared__ __align__(16) bf16_t P_lds[4][16][72];  // 9KB

    const bf16_t* Q = qfb + ((size_t)(b*16 + t)*1024 + p0 + w*16 + l15)*160 + l4*8;
    bf16x8 aq[5];
    #pragma unroll
    for (int kc = 0; kc < 5; kc++) aq[kc] = *(const bf16x8*)(Q + kc*32);

    f32x4 o[5] = {};

    for (int n0 = 0; n0 < 256; n0 += 64) {
        // ---- cooperative stage: K rows (n_base+n0 .. +63) x 160, coalesced ----
        const bf16_t* Ksrc = kfb + ((size_t)b*3072 + n_base + n0)*160;
        #pragma unroll
        for (int it = 0; it < 5; it++) {
            int idx = it*256 + tid;            // 0..1279 = 64 rows x 20 chunks
            int row = idx/20, ch = idx%20;
            *(bf16x8*)&K_lds[row][ch*8] = *(const bf16x8*)(Ksrc + (size_t)row*160 + ch*8);
        }
        // ---- cooperative stage: Vh rows 0..79, cols n_base+n0 .. +63 ----
        const bf16_t* Vsrc = vhT + (size_t)b*393216 + n_base + n0;
        #pragma unroll
        for (int it = 0; it < 3; it++) {
            int idx = it*256 + tid;            // 0..639 = 80 rows x 8 chunks
            if (idx < 640) {
                int row = idx >> 3, ch = idx & 7;
                *(bf16x8*)&V_lds[row][ch*8] = *(const bf16x8*)(Vsrc + (size_t)row*3072 + ch*8);
            }
        }
        __syncthreads();
        // ---- compute: S = Q K^T, P = exp(S), O += P Vh ----
        f32x4 s[4] = {};
        #pragma unroll
        for (int kc = 0; kc < 5; kc++) {
            #pragma unroll
            for (int nf = 0; nf < 4; nf++) {
                bf16x8 bk = *(const bf16x8*)&K_lds[nf*16 + l15][kc*32 + l4*8];
                s[nf] = MFMA16(aq[kc], bk, s[nf]);
            }
        }
        #pragma unroll
        for (int nf = 0; nf < 4; nf++) {
            #pragma unroll
            for (int rr = 0; rr < 4; rr++) {
                float pe = __expf(s[nf][rr]);
                P_lds[w][l4*4 + rr][nf*16 + l15] = (bf16_t)pe;
            }
        }
        #pragma unroll
        for (int kc2 = 0; kc2 < 2; kc2++) {
            bf16x8 ap = *(const bf16x8*)&P_lds[w][l15][kc2*32 + l4*8];
            #pragma unroll
            for (int cf = 0; cf < 5; cf++) {
                bf16x8 bv = *(const bf16x8*)&V_lds[cf*16 + l15][kc2*32 + l4*8];
                o[cf] = MFMA16(ap, bv, o[cf]);
            }
        }
        __syncthreads();                       // compute done before next stage
    }
    float* O = PVp + (size_t)sl*PVSTR + ((size_t)((b*5 + ts)*1024) + p0 + w*16)*72;
    #pragma unroll
    for (int cf = 0; cf < 5; cf++) {
        int cc = cf*16 + l15;
        if (cc < 66) {
            #pragma unroll
            for (int rr = 0; rr < 4; rr++)
                O[(size_t)(l4*4 + rr)*72 + cc] = o[cf][rr];
        }
    }
}

// ---------------- sequential 5-step chain; sums PV slices, divides by col65 ----------------
__global__ __launch_bounds__(256)
void k_chain2(const bf16_t* __restrict__ p16b, const float* __restrict__ PVp,
              const float* __restrict__ whhbuf, float* __restrict__ hidden,
              float* __restrict__ wmk, float* __restrict__ mh, int t0, int ph, int ns)
{
    int b = blockIdx.y;
    int tid = threadIdx.x, lane = tid & 63, w = tid >> 6;
    int p = blockIdx.x*4 + w;
    __shared__ float whh_s[64][66];
    __shared__ float hid_s[4][64];
    for (int idx = tid; idx < 64*66; idx += 256) whh_s[idx/66][idx%66] = whhbuf[idx];
    float h = hidden[((size_t)b*1024 + p)*64 + lane];
    hid_s[w][lane] = h;
    __syncthreads();
    float wd = whh_s[lane][64];
    for (int ts = 0; ts < 5; ts++) {
        int t = t0 + ts;
        size_t r16 = ((size_t)(b*16 + t)*1024 + p)*72;
        size_t rpv = ((size_t)((b*5 + ts)*1024) + p)*72;
        float pvc = 0.f, pv64 = 0.f, pv65 = 0.f;
        for (int s2 = 0; s2 < ns; s2++) {
            const float* bp = PVp + (size_t)s2*PVSTR + rpv;
            pvc  += bp[lane];
            pv64 += bp[64];
            pv65 += bp[65];
        }
        float rinv  = 1.f/pv65;
        float pre   = (float)p16b[r16 + lane] + pvc*rinv;
        float fgpre = (float)p16b[r16 + 64]   + pv64*rinv;
        float s = pre;
        #pragma unroll 8
        for (int k = 0; k < 64; k++) s += hid_s[w][k]*whh_s[k][lane];
        float hl = tanhf(s);
        float fgs = hl*wd;
        #pragma unroll
        for (int off = 1; off < 64; off <<= 1) fgs += __shfl_xor(fgs, off);
        float fg = fgpre + fgs;
        float m = 1.f/(1.f+expf(-fg));
        size_t rmh = ((size_t)(b*15 + ph*5 + ts)*1024 + p)*66;
        mh[rmh + lane] = m*hl;
        if (lane == 0) mh[rmh + 64] = m;
        if (ts == 4 && lane == 0) wmk[b*1024 + p] = m;
        h = hl;
        __syncthreads();
        hid_s[w][lane] = h;
        __syncthreads();
    }
    hidden[((size_t)b*1024 + p)*64 + lane] = h;
}

// ---------------- hidden update (MFMA): tanh([V | hid?] @ Wh2) ----------------
__global__ __launch_bounds__(256)
void k_hidm(const bf16_t* __restrict__ vb, const bf16_t* __restrict__ wh2T,
            float* __restrict__ hidden, int vslot, int has_h)
{
    int b = blockIdx.y, p0 = blockIdx.x*64;
    int tid = threadIdx.x, lane = tid & 63, w = tid >> 6;
    int l15 = lane & 15, l4 = lane >> 4;
    int arow = p0 + w*16 + l15;
    const bf16_t* A = vb + ((size_t)b*3072 + vslot*1024 + arow)*512;
    const float* Hp = hidden + ((size_t)b*1024 + arow)*64;
    f32x4 acc[4] = {};
    int kiters = has_h ? 18 : 16;
    for (int ks = 0; ks < kiters; ks++) {
        bf16x8 a0;
        if (ks < 16) a0 = *(const bf16x8*)(A + ks*32 + l4*8);
        else {
            int ko = (ks-16)*32 + l4*8;
            float4 h0 = *(const float4*)(Hp + ko);
            float4 h1 = *(const float4*)(Hp + ko + 4);
            a0[0]=(bf16_t)h0.x; a0[1]=(bf16_t)h0.y; a0[2]=(bf16_t)h0.z; a0[3]=(bf16_t)h0.w;
            a0[4]=(bf16_t)h1.x; a0[5]=(bf16_t)h1.y; a0[6]=(bf16_t)h1.z; a0[7]=(bf16_t)h1.w;
        }
        #pragma unroll
        for (int cf = 0; cf < 4; cf++) {
            bf16x8 bv = *(const bf16x8*)(wh2T + (size_t)(cf*16 + l15)*576 + ks*32 + l4*8);
            acc[cf] = MFMA16(a0, bv, acc[cf]);
        }
    }
    #pragma unroll
    for (int cf = 0; cf < 4; cf++) {
        int cc = cf*16 + l15;
        #pragma unroll
        for (int rr = 0; rr < 4; rr++) {
            int p = p0 + w*16 + l4*4 + rr;
            hidden[((size_t)b*1024 + p)*64 + cc] = tanhf(acc[cf][rr]);
        }
    }
}

// ---------------- feats t=1..15: weighted mean reduce ----------------
__global__ __launch_bounds__(256)
void k_feats(const float* __restrict__ mh, float* __restrict__ out)
{
    int slot = blockIdx.x, b = blockIdx.y, t = slot + 1;
    int tid = threadIdx.x, c = tid & 63, g = tid >> 6;
    const float* base = mh + (size_t)(b*15 + slot)*1024*66;
    float s = 0.f, sm = 0.f;
    for (int p = g; p < 1024; p += 4) {
        s += base[(size_t)p*66 + c];
        if (c == 0) sm += base[(size_t)p*66 + 64];
    }
    __shared__ float red[4][64];
    __shared__ float redm[4];
    red[g][c] = s;
    if (c == 0) redm[g] = sm;
    __syncthreads();
    if (g == 0) {
        float tot  = red[0][c] + red[1][c] + red[2][c] + red[3][c];
        float totm = redm[0] + redm[1] + redm[2] + redm[3];
        out[(size_t)(b*16 + t)*64 + c] = tot / fmaxf(totm, 1e-6f);
    }
}

// ---------------- host launcher ----------------
extern "C" void kernel_launch(void* const* d_in, const int* in_sizes, int n_in,
                              void* d_out, int out_size, void* d_ws, size_t ws_size,
                              hipStream_t stream)
{
    (void)in_sizes; (void)n_in; (void)out_size;
    if (ws_size < ws_need*sizeof(float)) return;
    const float* frames = (const float*)d_in[0];
    const float* imask  = (const float*)d_in[1];
    const float* Wk   = (const float*)d_in[3];
    const float* Wsh  = (const float*)d_in[4];
    const float* Wse  = (const float*)d_in[5];
    const float* Wf   = (const float*)d_in[6];
    const float* Wv   = (const float*)d_in[7];
    const float* Wh2  = (const float*)d_in[8];
    const float* Whd  = (const float*)d_in[9];
    const float* Wdec = (const float*)d_in[10];
    float* out = (float*)d_out;
    float* ws  = (float*)d_ws;

    bf16_t* wcatT = (bf16_t*)(ws + o_wcatT);
    bf16_t* whfT  = (bf16_t*)(ws + o_whfT);
    bf16_t* wvhT  = (bf16_t*)(ws + o_wvhT);
    float*  wvh1  = ws + o_wvh1;
    bf16_t* WvT   = (bf16_t*)(ws + o_WvT);
    float*  whh   = ws + o_whh;
    bf16_t* wh2T  = (bf16_t*)(ws + o_wh2T);
    bf16_t* keyb  = (bf16_t*)(ws + o_keyb);
    float*  msb   = ws + o_ms;
    bf16_t* qeb   = (bf16_t*)(ws + o_qeb);
    bf16_t* f16b  = (bf16_t*)(ws + o_f16b);
    bf16_t* qfb   = (bf16_t*)(ws + o_qfb);
    bf16_t* kfb   = (bf16_t*)(ws + o_kfb);
    bf16_t* vb    = (bf16_t*)(ws + o_vb);
    bf16_t* vhT   = (bf16_t*)(ws + o_vhT);
    float*  PVp   = ws + o_pv;
    bf16_t* p16b  = (bf16_t*)(ws + o_p16);
    float*  mh    = ws + o_mh;
    float*  hid   = ws + o_hid;
    float*  wmk   = ws + o_wmk;

    k_init<<<2226, 256, 0, stream>>>(Wk, Wsh, Wse, Wf, Wv, Wh2, Whd, Wdec,
                                     wcatT, whfT, WvT, whh, wh2T, out, wvhT, wvh1);
    k_proj<<<dim3(16,16), 512, 0, stream>>>(frames, wcatT, keyb, msb, qeb, f16b);
    k_qf<<<dim3(32,128), dim3(64,8), 0, stream>>>(keyb, qeb, qfb, out);
    k_mask0<<<64, 256, 0, stream>>>(imask, wmk);
    k_prep<<<dim3(32,2), 128, 0, stream>>>(f16b, keyb, msb, wmk, wvhT, wvh1, kfb, vhT, 0, 0);
    k_value<<<dim3(8,16,2), 256, 0, stream>>>(f16b, wmk, WvT, Wv, vb, 0, 0);
    k_hidm<<<dim3(16,2), 256, 0, stream>>>(vb, wh2T, hid, 0, 0);
    k_pre16<<<dim3(16,32), 256, 0, stream>>>(f16b, whfT, p16b);

    for (int ph = 0; ph < 3; ph++) {
        int t0 = 1 + ph*5;
        int ns = (ph + 1)*4;            // N/256 slices: 4, 8, 12
        k_att<<<dim3(16,5,2*ns), 256, 0, stream>>>(qfb, kfb, vhT, PVp, t0);
        k_chain2<<<dim3(256,2), 256, 0, stream>>>(p16b, PVp, whh, hid, wmk, mh, t0, ph, ns);
        if (ph < 2) {
            int tm = t0 + 4, slot = ph + 1;
            k_prep<<<dim3(32,2), 128, 0, stream>>>(f16b, keyb, msb, wmk, wvhT, wvh1, kfb, vhT, tm, slot);
            if (ph == 1) {
                k_value<<<dim3(8,16,2), 256, 0, stream>>>(f16b, wmk, WvT, Wv, vb, tm, slot);
                k_hidm<<<dim3(16,2), 256, 0, stream>>>(vb, wh2T, hid, 2, 1);
            }
        }
    }
    k_feats<<<dim3(15,2), 256, 0, stream>>>(mh, out);
}